// Round 1
// baseline (741.856 us; speedup 1.0000x reference)
//
#include <hip/hip_runtime.h>
#include <cstdint>
#include <cstddef>

typedef __attribute__((ext_vector_type(8))) short short8;
typedef __attribute__((ext_vector_type(4))) float f32x4;

#define DEVI static __device__ __forceinline__

DEVI float bf2f(unsigned short b) {
  union { unsigned int u; float f; } v; v.u = ((unsigned int)b) << 16; return v.f;
}
DEVI unsigned short f2bf(float f) {
  union { float f; unsigned int u; } v; v.f = f;
  unsigned int r = v.u + 0x7fffu + ((v.u >> 16) & 1u);   // RTNE
  return (unsigned short)(r >> 16);
}

DEVI void gload16(const void* g, void* l) {
  __builtin_amdgcn_global_load_lds(
      (const __attribute__((address_space(1))) void*)g,
      (__attribute__((address_space(3))) void*)l, 16, 0, 0);
}

// ---------------------------------------------------------------------------
// elementwise f32 -> bf16 (vectorized float4 -> ushort4)
// ---------------------------------------------------------------------------
__global__ __launch_bounds__(256) void f32_to_bf16_kern(
    const float* __restrict__ in, unsigned short* __restrict__ out, int n4)
{
  int i = blockIdx.x * blockDim.x + threadIdx.x;
  int stride = gridDim.x * blockDim.x;
  for (; i < n4; i += stride) {
    float4 f = ((const float4*)in)[i];
    ushort4 u;
    u.x = f2bf(f.x); u.y = f2bf(f.y); u.z = f2bf(f.z); u.w = f2bf(f.w);
    ((ushort4*)out)[i] = u;
  }
}

// ---------------------------------------------------------------------------
// transpose + convert: in f32 [Kd][Nd]  ->  out bf16 [Nd][Kd]   (64x64 tiles)
// ---------------------------------------------------------------------------
__global__ __launch_bounds__(256) void transpose_f32_bf16(
    const float* __restrict__ in, unsigned short* __restrict__ out, int Kd, int Nd)
{
  __shared__ unsigned short tile[64][72];   // row stride 144B (16B aligned)
  int n0 = blockIdx.x * 64, k0 = blockIdx.y * 64;
  int t = threadIdx.x;
  int r = t >> 2, cg = (t & 3) * 16;
  const float* src = in + (size_t)(k0 + r) * Nd + n0 + cg;
#pragma unroll
  for (int q = 0; q < 16; q += 4) {
    float4 f = *(const float4*)(src + q);
    ushort4 u;
    u.x = f2bf(f.x); u.y = f2bf(f.y); u.z = f2bf(f.z); u.w = f2bf(f.w);
    *(ushort4*)&tile[r][cg + q] = u;
  }
  __syncthreads();
  unsigned int p[8];
#pragma unroll
  for (int q = 0; q < 8; ++q)
    p[q] = (unsigned int)tile[cg + 2*q][r] | ((unsigned int)tile[cg + 2*q + 1][r] << 16);
  unsigned short* dst = out + (size_t)(n0 + r) * Kd + k0 + cg;
  *(uint4*)dst       = make_uint4(p[0], p[1], p[2], p[3]);
  *(uint4*)(dst + 8) = make_uint4(p[4], p[5], p[6], p[7]);
}

// ---------------------------------------------------------------------------
// bf16 transpose per head: in [rows][cols] -> out [cols][rows], 64x64 tiles
// blockIdx.z = head (contiguous head stride rows*cols both sides)
// ---------------------------------------------------------------------------
__global__ __launch_bounds__(256) void transpose_bf16_64(
    const unsigned short* __restrict__ in, unsigned short* __restrict__ out,
    int rows, int cols)
{
  __shared__ unsigned short tile[64][72];
  size_t hoff = (size_t)blockIdx.z * rows * cols;
  int e0 = blockIdx.x * 64, s0 = blockIdx.y * 64;
  int t = threadIdx.x;
  int r = t >> 2, cg = (t & 3) * 16;
  const unsigned short* src = in + hoff + (size_t)(s0 + r) * cols + e0 + cg;
  *(uint4*)&tile[r][cg]     = *(const uint4*)src;
  *(uint4*)&tile[r][cg + 8] = *(const uint4*)(src + 8);
  __syncthreads();
  unsigned int p[8];
#pragma unroll
  for (int q = 0; q < 8; ++q)
    p[q] = (unsigned int)tile[cg + 2*q][r] | ((unsigned int)tile[cg + 2*q + 1][r] << 16);
  unsigned short* dst = out + hoff + (size_t)(e0 + r) * rows + s0 + cg;
  *(uint4*)dst       = make_uint4(p[0], p[1], p[2], p[3]);
  *(uint4*)(dst + 8) = make_uint4(p[4], p[5], p[6], p[7]);
}

// ---------------------------------------------------------------------------
// GEMM: C[M][Nn] = A[M][K] * Bt[Nn][K]^T  (+bias), bf16 in, f32 acc
// 128x128 tile, BK=32, 4 waves (2x2), 4x4 16x16x32 MFMA per wave
// ---------------------------------------------------------------------------
template<int HAS_BIAS, int OUT_BF16>
__global__ __launch_bounds__(256, 2) void gemm_bt(
    const unsigned short* __restrict__ A, const unsigned short* __restrict__ Bt,
    const float* __restrict__ bias, void* __restrict__ Cout,
    int M, int Nn, int K)
{
  __shared__ unsigned short lsA[128 * 32];
  __shared__ unsigned short lsB[128 * 32];
  const int tid = threadIdx.x;
  const int w = tid >> 6, lane = tid & 63;
  const int wr = w >> 1, wc = w & 1;
  const int l15 = lane & 15, lhi = lane >> 4;
  const int bx = blockIdx.x, by = blockIdx.y;

  f32x4 acc[4][4];
#pragma unroll
  for (int i = 0; i < 4; ++i)
#pragma unroll
    for (int j = 0; j < 4; ++j) acc[i][j] = (f32x4){0.f, 0.f, 0.f, 0.f};

  int rr[2], kk8[2], ldsoff[2];
#pragma unroll
  for (int j = 0; j < 2; ++j) {
    int c = j * 256 + w * 64 + lane;       // 16B chunk id in 128x32 tile
    rr[j] = c >> 2; kk8[j] = (c & 3) * 8;
    ldsoff[j] = (j * 256 + w * 64) * 16;   // wave-uniform LDS byte base
  }
  const unsigned short* Abase = A + (size_t)(by * 128) * K;
  const unsigned short* Bbase = Bt + (size_t)(bx * 128) * K;

  for (int k0 = 0; k0 < K; k0 += 32) {
#pragma unroll
    for (int j = 0; j < 2; ++j) {
      gload16(Abase + (size_t)rr[j] * K + k0 + kk8[j], (char*)lsA + ldsoff[j]);
      gload16(Bbase + (size_t)rr[j] * K + k0 + kk8[j], (char*)lsB + ldsoff[j]);
    }
    __syncthreads();
    short8 af[4], bf[4];
#pragma unroll
    for (int t = 0; t < 4; ++t) {
      af[t] = *(const short8*)&lsA[(wr * 64 + t * 16 + l15) * 32 + lhi * 8];
      bf[t] = *(const short8*)&lsB[(wc * 64 + t * 16 + l15) * 32 + lhi * 8];
    }
#pragma unroll
    for (int mt = 0; mt < 4; ++mt)
#pragma unroll
      for (int nt = 0; nt < 4; ++nt)
        acc[mt][nt] = __builtin_amdgcn_mfma_f32_16x16x32_bf16(af[mt], bf[nt], acc[mt][nt], 0, 0, 0);
    __syncthreads();
  }

  const int nbase = bx * 128 + wc * 64;
  const int mbase = by * 128 + wr * 64;
  float bv[4];
  if (HAS_BIAS) {
#pragma unroll
    for (int nt = 0; nt < 4; ++nt) bv[nt] = bias[nbase + nt * 16 + l15];
  }
#pragma unroll
  for (int mt = 0; mt < 4; ++mt)
#pragma unroll
    for (int nt = 0; nt < 4; ++nt) {
#pragma unroll
      for (int r2 = 0; r2 < 4; ++r2) {
        int m = mbase + mt * 16 + lhi * 4 + r2;
        int n = nbase + nt * 16 + l15;
        float v = acc[mt][nt][r2];
        if (HAS_BIAS) v += bv[nt];
        if (OUT_BF16) ((unsigned short*)Cout)[(size_t)m * Nn + n] = f2bf(v);
        else          ((float*)Cout)[(size_t)m * Nn + n] = v;
      }
    }
}

// ---------------------------------------------------------------------------
// fused RMSNorm + RoPE + head split/concat
// wave = one (s, h); s<2048 spatial (rope), else prompt row s-2048
// ---------------------------------------------------------------------------
__global__ __launch_bounds__(256) void fuse_rms_rope(
    const unsigned short* __restrict__ qkv,  // [2048][9216] bf16
    const unsigned short* __restrict__ aqkv, // [256][9216] bf16
    const float* __restrict__ nq, const float* __restrict__ nk,
    const float* __restrict__ naq, const float* __restrict__ nak,
    const float* __restrict__ ctab, const float* __restrict__ stab,
    unsigned short* __restrict__ Qf, unsigned short* __restrict__ Kf,
    unsigned short* __restrict__ Vf)
{
  int wid = blockIdx.x * 4 + (threadIdx.x >> 6);
  int lane = threadIdx.x & 63;
  int h = wid / 2304, s = wid % 2304;
  bool sp = (s < 2048);
  const unsigned short* src = sp ? (qkv + (size_t)s * 9216)
                                 : (aqkv + (size_t)(s - 2048) * 9216);
  int e = lane * 2;
  ushort2 qu = *(const ushort2*)&src[h * 128 + e];
  ushort2 ku = *(const ushort2*)&src[3072 + h * 128 + e];
  ushort2 vu = *(const ushort2*)&src[6144 + h * 128 + e];
  float q0 = bf2f(qu.x), q1 = bf2f(qu.y);
  float k0 = bf2f(ku.x), k1 = bf2f(ku.y);
  float sq = q0 * q0 + q1 * q1, sk = k0 * k0 + k1 * k1;
#pragma unroll
  for (int mm = 1; mm < 64; mm <<= 1) {
    sq += __shfl_xor(sq, mm);
    sk += __shfl_xor(sk, mm);
  }
  float rq = rsqrtf(sq * (1.f / 128.f) + 1e-5f);
  float rk = rsqrtf(sk * (1.f / 128.f) + 1e-5f);
  const float* wq = sp ? nq : naq;
  const float* wk = sp ? nk : nak;
  q0 *= rq * wq[e]; q1 *= rq * wq[e + 1];
  k0 *= rk * wk[e]; k1 *= rk * wk[e + 1];
  if (sp) {
    float c0 = ctab[s * 128 + e], c1 = ctab[s * 128 + e + 1];
    float s0 = stab[s * 128 + e], s1 = stab[s * 128 + e + 1];
    float a0 = q0 * c0 - q1 * s0, a1 = q1 * c1 + q0 * s1;
    float b0 = k0 * c0 - k1 * s0, b1 = k1 * c1 + k0 * s1;
    q0 = a0; q1 = a1; k0 = b0; k1 = b1;
  }
  size_t o = (size_t)h * 2304 * 128 + (size_t)s * 128 + e;
  *(ushort2*)&Qf[o] = make_ushort2(f2bf(q0), f2bf(q1));
  *(ushort2*)&Kf[o] = make_ushort2(f2bf(k0), f2bf(k1));
  *(ushort2*)&Vf[o] = vu;
}

// ---------------------------------------------------------------------------
// flash attention: block = (head, 64-query tile), 4 waves x 16 queries
// K tiles of 64 staged to LDS; Vt [128][2304] tiles staged to LDS
// ---------------------------------------------------------------------------
__global__ __launch_bounds__(256, 2) void attn_fwd(
    const unsigned short* __restrict__ Qf, const unsigned short* __restrict__ Kf,
    const unsigned short* __restrict__ Vt, unsigned short* __restrict__ Om)
{
  __shared__ unsigned short lsK[64 * 128];
  __shared__ unsigned short lsV[128 * 64];
  __shared__ unsigned short lsP[4 * 16 * 64];
  int h = blockIdx.x / 36, qt = blockIdx.x % 36;
  int q0 = qt * 64;
  int tid = threadIdx.x, w = tid >> 6, lane = tid & 63;
  int l15 = lane & 15, lhi = lane >> 4;
  const size_t headO = (size_t)h * 2304 * 128;

  short8 qf[4];
  {
    const unsigned short* qrow = Qf + headO + (size_t)(q0 + w * 16 + l15) * 128;
#pragma unroll
    for (int kk = 0; kk < 4; ++kk)
      qf[kk] = *(const short8*)&qrow[kk * 32 + lhi * 8];
  }
  float m[4], lsum[4];
  f32x4 accO[8];
#pragma unroll
  for (int r = 0; r < 4; ++r) { m[r] = -1e30f; lsum[r] = 0.f; }
#pragma unroll
  for (int t = 0; t < 8; ++t) accO[t] = (f32x4){0.f, 0.f, 0.f, 0.f};

  const float scale = 0.08838834764831845f;  // 1/sqrt(128)

  int rK[4], iK[4], rV[4], iV[4], loff[4];
#pragma unroll
  for (int j = 0; j < 4; ++j) {
    int c = j * 256 + w * 64 + lane;            // 16B chunk
    rK[j] = c >> 4; iK[j] = (c & 15) * 8;       // [64][128] tile
    rV[j] = c >> 3; iV[j] = (c & 7) * 8;        // [128][64] tile
    loff[j] = (j * 256 + w * 64) * 16;
  }

  for (int kb = 0; kb < 2304; kb += 64) {
    const unsigned short* kbase = Kf + headO + (size_t)kb * 128;
    const unsigned short* vbase = Vt + headO + kb;
#pragma unroll
    for (int j = 0; j < 4; ++j) {
      gload16(kbase + (size_t)rK[j] * 128 + iK[j], (char*)lsK + loff[j]);
      gload16(vbase + (size_t)rV[j] * 2304 + iV[j], (char*)lsV + loff[j]);
    }
    __syncthreads();

    // S = Q K^T for this wave's 16 query rows x 64 keys
    f32x4 accS[4];
#pragma unroll
    for (int ct = 0; ct < 4; ++ct) {
      accS[ct] = (f32x4){0.f, 0.f, 0.f, 0.f};
#pragma unroll
      for (int kk = 0; kk < 4; ++kk) {
        short8 kfr = *(const short8*)&lsK[(ct * 16 + l15) * 128 + kk * 32 + lhi * 8];
        accS[ct] = __builtin_amdgcn_mfma_f32_16x16x32_bf16(qf[kk], kfr, accS[ct], 0, 0, 0);
      }
    }

    // online softmax per row
#pragma unroll
    for (int r = 0; r < 4; ++r) {
      float s0 = accS[0][r] * scale, s1 = accS[1][r] * scale;
      float s2 = accS[2][r] * scale, s3 = accS[3][r] * scale;
      float tmax = fmaxf(fmaxf(s0, s1), fmaxf(s2, s3));
#pragma unroll
      for (int mm = 1; mm < 16; mm <<= 1) tmax = fmaxf(tmax, __shfl_xor(tmax, mm));
      float mnew = fmaxf(m[r], tmax);
      float corr = __expf(m[r] - mnew);
      float p0 = __expf(s0 - mnew), p1 = __expf(s1 - mnew);
      float p2 = __expf(s2 - mnew), p3 = __expf(s3 - mnew);
      float psum = p0 + p1 + p2 + p3;
#pragma unroll
      for (int mm = 1; mm < 16; mm <<= 1) psum += __shfl_xor(psum, mm);
      lsum[r] = lsum[r] * corr + psum;
      m[r] = mnew;
#pragma unroll
      for (int t = 0; t < 8; ++t) accO[t][r] *= corr;
      int rowl = lhi * 4 + r;
      unsigned short* pp = &lsP[w * 1024 + rowl * 64 + l15];
      pp[0] = f2bf(p0); pp[16] = f2bf(p1); pp[32] = f2bf(p2); pp[48] = f2bf(p3);
    }
    __syncthreads();

    // O += P V
#pragma unroll
    for (int kk = 0; kk < 2; ++kk) {
      short8 pf = *(const short8*)&lsP[w * 1024 + l15 * 64 + kk * 32 + lhi * 8];
#pragma unroll
      for (int et = 0; et < 8; ++et) {
        short8 vf = *(const short8*)&lsV[(et * 16 + l15) * 64 + kk * 32 + lhi * 8];
        accO[et] = __builtin_amdgcn_mfma_f32_16x16x32_bf16(pf, vf, accO[et], 0, 0, 0);
      }
    }
    __syncthreads();
  }

#pragma unroll
  for (int r = 0; r < 4; ++r) {
    float inv = 1.0f / lsum[r];
    int row = q0 + w * 16 + lhi * 4 + r;
    unsigned short* orow = Om + (size_t)row * 3072 + h * 128;
#pragma unroll
    for (int et = 0; et < 8; ++et)
      orow[et * 16 + l15] = f2bf(accO[et][r] * inv);
  }
}

// ---------------------------------------------------------------------------
extern "C" void kernel_launch(void* const* d_in, const int* in_sizes, int n_in,
                              void* d_out, int out_size, void* d_ws, size_t ws_size,
                              hipStream_t stream)
{
  const float* spatial      = (const float*)d_in[0];
  const float* prompt       = (const float*)d_in[1];
  const float* w_qkv        = (const float*)d_in[2];
  const float* w_add_qkv    = (const float*)d_in[3];
  const float* b_add_qkv    = (const float*)d_in[4];
  const float* norm_q_w     = (const float*)d_in[5];
  const float* norm_k_w     = (const float*)d_in[6];
  const float* norm_add_q_w = (const float*)d_in[7];
  const float* norm_add_k_w = (const float*)d_in[8];
  const float* w_out        = (const float*)d_in[9];
  const float* b_out        = (const float*)d_in[10];
  const float* w_add_out    = (const float*)d_in[11];
  const float* b_add_out    = (const float*)d_in[12];
  const float* rope_cos     = (const float*)d_in[13];
  const float* rope_sin     = (const float*)d_in[14];

  // workspace layout (bytes, 256-aligned), with lifetime-based reuse
  constexpr size_t O_WTQ  = 0;                       // wT_qkv  [9216][3072]  56,623,104
  constexpr size_t O_WTAQ = 56623104;                // wT_add_qkv [9216][1536] 28,311,552
  constexpr size_t O_SPAT = 84934656;                // spatial bf16          12,582,912
  constexpr size_t O_PROM = 97517568;                // prompt bf16              786,432
  constexpr size_t O_QKV  = 98304000;                // qkv_s [2048][9216]    37,748,736
  constexpr size_t O_AQKV = 136052736;               // aqkv [256][9216]       4,718,592
  constexpr size_t O_QF   = 140771328;               // Qf                    14,155,776
  constexpr size_t O_KF   = 154927104;               // Kf
  constexpr size_t O_VF   = 169082880;               // Vf
  constexpr size_t TOTAL  = 183238656;
  constexpr size_t O_WTO  = O_WTQ;                   // wT_out (reuse after gemm1)
  constexpr size_t O_WTAO = O_WTQ + 18874368;        // wT_add_out
  constexpr size_t O_VT   = O_QKV;                   // Vt (reuse after fuse)
  constexpr size_t O_ATTN = O_WTAQ;                  // attn_out (reuse after gemm2)
  if (ws_size < TOTAL) return;

  char* ws = (char*)d_ws;
  unsigned short* wTq      = (unsigned short*)(ws + O_WTQ);
  unsigned short* wTaq     = (unsigned short*)(ws + O_WTAQ);
  unsigned short* spat_bf  = (unsigned short*)(ws + O_SPAT);
  unsigned short* prom_bf  = (unsigned short*)(ws + O_PROM);
  unsigned short* qkv_s    = (unsigned short*)(ws + O_QKV);
  unsigned short* aqkv     = (unsigned short*)(ws + O_AQKV);
  unsigned short* Qf       = (unsigned short*)(ws + O_QF);
  unsigned short* Kf       = (unsigned short*)(ws + O_KF);
  unsigned short* Vf       = (unsigned short*)(ws + O_VF);
  unsigned short* wTo      = (unsigned short*)(ws + O_WTO);
  unsigned short* wTao     = (unsigned short*)(ws + O_WTAO);
  unsigned short* Vt       = (unsigned short*)(ws + O_VT);
  unsigned short* attn_out = (unsigned short*)(ws + O_ATTN);

  // activation converts
  f32_to_bf16_kern<<<2048, 256, 0, stream>>>(spatial, spat_bf, 2048 * 3072 / 4);
  f32_to_bf16_kern<<<384, 256, 0, stream>>>(prompt, prom_bf, 256 * 1536 / 4);
  // weight transposes (f32 [K][N] -> bf16 [N][K])
  transpose_f32_bf16<<<dim3(144, 48), 256, 0, stream>>>(w_qkv, wTq, 3072, 9216);
  transpose_f32_bf16<<<dim3(144, 24), 256, 0, stream>>>(w_add_qkv, wTaq, 1536, 9216);
  // QKV projections
  gemm_bt<0, 1><<<dim3(72, 16), 256, 0, stream>>>(spat_bf, wTq, nullptr, qkv_s, 2048, 9216, 3072);
  gemm_bt<1, 1><<<dim3(72, 2), 256, 0, stream>>>(prom_bf, wTaq, b_add_qkv, aqkv, 256, 9216, 1536);
  // RMSNorm + RoPE + head split
  fuse_rms_rope<<<13824, 256, 0, stream>>>(qkv_s, aqkv, norm_q_w, norm_k_w,
                                           norm_add_q_w, norm_add_k_w,
                                           rope_cos, rope_sin, Qf, Kf, Vf);
  // V transpose per head: [2304][128] -> [128][2304]
  transpose_bf16_64<<<dim3(2, 36, 24), 256, 0, stream>>>(Vf, Vt, 2304, 128);
  // attention
  attn_fwd<<<24 * 36, 256, 0, stream>>>(Qf, Kf, Vt, attn_out);
  // output-projection weight transposes
  transpose_f32_bf16<<<dim3(48, 48), 256, 0, stream>>>(w_out, wTo, 3072, 3072);
  transpose_f32_bf16<<<dim3(48, 48), 256, 0, stream>>>(w_add_out, wTao, 3072, 3072);
  // output projections (f32 out + bias) straight into d_out
  gemm_bt<1, 0><<<dim3(24, 16), 256, 0, stream>>>(attn_out, wTo, b_out,
                                                  (float*)d_out, 2048, 3072, 3072);
  gemm_bt<1, 0><<<dim3(24, 2), 256, 0, stream>>>(attn_out + (size_t)2048 * 3072, wTao, b_add_out,
                                                 (float*)d_out + 6291456, 256, 3072, 3072);
}

// Round 2
// 596.171 us; speedup vs baseline: 1.2444x; 1.2444x over previous
//
#include <hip/hip_runtime.h>
#include <cstdint>
#include <cstddef>

typedef __attribute__((ext_vector_type(8))) short short8;
typedef __attribute__((ext_vector_type(4))) float f32x4;

#define DEVI static __device__ __forceinline__

DEVI float bf2f(unsigned short b) {
  union { unsigned int u; float f; } v; v.u = ((unsigned int)b) << 16; return v.f;
}
DEVI unsigned short f2bf(float f) {
  union { float f; unsigned int u; } v; v.f = f;
  unsigned int r = v.u + 0x7fffu + ((v.u >> 16) & 1u);   // RTNE
  return (unsigned short)(r >> 16);
}

DEVI void gload16(const void* g, void* l) {
  __builtin_amdgcn_global_load_lds(
      (const __attribute__((address_space(1))) void*)g,
      (__attribute__((address_space(3))) void*)l, 16, 0, 0);
}

// ---------------------------------------------------------------------------
// elementwise f32 -> bf16 (vectorized float4 -> ushort4)
// ---------------------------------------------------------------------------
__global__ __launch_bounds__(256) void f32_to_bf16_kern(
    const float* __restrict__ in, unsigned short* __restrict__ out, int n4)
{
  int i = blockIdx.x * blockDim.x + threadIdx.x;
  int stride = gridDim.x * blockDim.x;
  for (; i < n4; i += stride) {
    float4 f = ((const float4*)in)[i];
    ushort4 u;
    u.x = f2bf(f.x); u.y = f2bf(f.y); u.z = f2bf(f.z); u.w = f2bf(f.w);
    ((ushort4*)out)[i] = u;
  }
}

// ---------------------------------------------------------------------------
// transpose + convert: in f32 [Kd][Nd]  ->  out bf16 [Nd][Kd]   (64x64 tiles)
// ---------------------------------------------------------------------------
__global__ __launch_bounds__(256) void transpose_f32_bf16(
    const float* __restrict__ in, unsigned short* __restrict__ out, int Kd, int Nd)
{
  __shared__ unsigned short tile[64][72];   // row stride 144B (16B aligned)
  int n0 = blockIdx.x * 64, k0 = blockIdx.y * 64;
  int t = threadIdx.x;
  int r = t >> 2, cg = (t & 3) * 16;
  const float* src = in + (size_t)(k0 + r) * Nd + n0 + cg;
#pragma unroll
  for (int q = 0; q < 16; q += 4) {
    float4 f = *(const float4*)(src + q);
    ushort4 u;
    u.x = f2bf(f.x); u.y = f2bf(f.y); u.z = f2bf(f.z); u.w = f2bf(f.w);
    *(ushort4*)&tile[r][cg + q] = u;
  }
  __syncthreads();
  unsigned int p[8];
#pragma unroll
  for (int q = 0; q < 8; ++q)
    p[q] = (unsigned int)tile[cg + 2*q][r] | ((unsigned int)tile[cg + 2*q + 1][r] << 16);
  unsigned short* dst = out + (size_t)(n0 + r) * Kd + k0 + cg;
  *(uint4*)dst       = make_uint4(p[0], p[1], p[2], p[3]);
  *(uint4*)(dst + 8) = make_uint4(p[4], p[5], p[6], p[7]);
}

// ---------------------------------------------------------------------------
// bf16 transpose per head: in [rows][cols] -> out [cols][rows], 64x64 tiles
// ---------------------------------------------------------------------------
__global__ __launch_bounds__(256) void transpose_bf16_64(
    const unsigned short* __restrict__ in, unsigned short* __restrict__ out,
    int rows, int cols)
{
  __shared__ unsigned short tile[64][72];
  size_t hoff = (size_t)blockIdx.z * rows * cols;
  int e0 = blockIdx.x * 64, s0 = blockIdx.y * 64;
  int t = threadIdx.x;
  int r = t >> 2, cg = (t & 3) * 16;
  const unsigned short* src = in + hoff + (size_t)(s0 + r) * cols + e0 + cg;
  *(uint4*)&tile[r][cg]     = *(const uint4*)src;
  *(uint4*)&tile[r][cg + 8] = *(const uint4*)(src + 8);
  __syncthreads();
  unsigned int p[8];
#pragma unroll
  for (int q = 0; q < 8; ++q)
    p[q] = (unsigned int)tile[cg + 2*q][r] | ((unsigned int)tile[cg + 2*q + 1][r] << 16);
  unsigned short* dst = out + hoff + (size_t)(e0 + r) * rows + s0 + cg;
  *(uint4*)dst       = make_uint4(p[0], p[1], p[2], p[3]);
  *(uint4*)(dst + 8) = make_uint4(p[4], p[5], p[6], p[7]);
}

// ---------------------------------------------------------------------------
// GEMM: C[M][Nn] = A[M][K] * Bt[Nn][K]^T  (+bias), bf16 in, f32 acc
// ---------------------------------------------------------------------------
template<int HAS_BIAS, int OUT_BF16>
__global__ __launch_bounds__(256, 2) void gemm_bt(
    const unsigned short* __restrict__ A, const unsigned short* __restrict__ Bt,
    const float* __restrict__ bias, void* __restrict__ Cout,
    int M, int Nn, int K)
{
  __shared__ unsigned short lsA[128 * 32];
  __shared__ unsigned short lsB[128 * 32];
  const int tid = threadIdx.x;
  const int w = tid >> 6, lane = tid & 63;
  const int wr = w >> 1, wc = w & 1;
  const int l15 = lane & 15, lhi = lane >> 4;
  const int bx = blockIdx.x, by = blockIdx.y;

  f32x4 acc[4][4];
#pragma unroll
  for (int i = 0; i < 4; ++i)
#pragma unroll
    for (int j = 0; j < 4; ++j) acc[i][j] = (f32x4){0.f, 0.f, 0.f, 0.f};

  int rr[2], kk8[2], ldsoff[2];
#pragma unroll
  for (int j = 0; j < 2; ++j) {
    int c = j * 256 + w * 64 + lane;
    rr[j] = c >> 2; kk8[j] = (c & 3) * 8;
    ldsoff[j] = (j * 256 + w * 64) * 16;
  }
  const unsigned short* Abase = A + (size_t)(by * 128) * K;
  const unsigned short* Bbase = Bt + (size_t)(bx * 128) * K;

  for (int k0 = 0; k0 < K; k0 += 32) {
#pragma unroll
    for (int j = 0; j < 2; ++j) {
      gload16(Abase + (size_t)rr[j] * K + k0 + kk8[j], (char*)lsA + ldsoff[j]);
      gload16(Bbase + (size_t)rr[j] * K + k0 + kk8[j], (char*)lsB + ldsoff[j]);
    }
    __syncthreads();
    short8 af[4], bf[4];
#pragma unroll
    for (int t = 0; t < 4; ++t) {
      af[t] = *(const short8*)&lsA[(wr * 64 + t * 16 + l15) * 32 + lhi * 8];
      bf[t] = *(const short8*)&lsB[(wc * 64 + t * 16 + l15) * 32 + lhi * 8];
    }
#pragma unroll
    for (int mt = 0; mt < 4; ++mt)
#pragma unroll
      for (int nt = 0; nt < 4; ++nt)
        acc[mt][nt] = __builtin_amdgcn_mfma_f32_16x16x32_bf16(af[mt], bf[nt], acc[mt][nt], 0, 0, 0);
    __syncthreads();
  }

  const int nbase = bx * 128 + wc * 64;
  const int mbase = by * 128 + wr * 64;
  float bv[4];
  if (HAS_BIAS) {
#pragma unroll
    for (int nt = 0; nt < 4; ++nt) bv[nt] = bias[nbase + nt * 16 + l15];
  }
#pragma unroll
  for (int mt = 0; mt < 4; ++mt)
#pragma unroll
    for (int nt = 0; nt < 4; ++nt) {
#pragma unroll
      for (int r2 = 0; r2 < 4; ++r2) {
        int m = mbase + mt * 16 + lhi * 4 + r2;
        int n = nbase + nt * 16 + l15;
        float v = acc[mt][nt][r2];
        if (HAS_BIAS) v += bv[nt];
        if (OUT_BF16) ((unsigned short*)Cout)[(size_t)m * Nn + n] = f2bf(v);
        else          ((float*)Cout)[(size_t)m * Nn + n] = v;
      }
    }
}

// ---------------------------------------------------------------------------
// fused RMSNorm + RoPE + head split/concat (+ fold softmax scale into Q)
// ---------------------------------------------------------------------------
__global__ __launch_bounds__(256) void fuse_rms_rope(
    const unsigned short* __restrict__ qkv,
    const unsigned short* __restrict__ aqkv,
    const float* __restrict__ nq, const float* __restrict__ nk,
    const float* __restrict__ naq, const float* __restrict__ nak,
    const float* __restrict__ ctab, const float* __restrict__ stab,
    unsigned short* __restrict__ Qf, unsigned short* __restrict__ Kf,
    unsigned short* __restrict__ Vf)
{
  int wid = blockIdx.x * 4 + (threadIdx.x >> 6);
  int lane = threadIdx.x & 63;
  int h = wid / 2304, s = wid % 2304;
  bool sp = (s < 2048);
  const unsigned short* src = sp ? (qkv + (size_t)s * 9216)
                                 : (aqkv + (size_t)(s - 2048) * 9216);
  int e = lane * 2;
  ushort2 qu = *(const ushort2*)&src[h * 128 + e];
  ushort2 ku = *(const ushort2*)&src[3072 + h * 128 + e];
  ushort2 vu = *(const ushort2*)&src[6144 + h * 128 + e];
  float q0 = bf2f(qu.x), q1 = bf2f(qu.y);
  float k0 = bf2f(ku.x), k1 = bf2f(ku.y);
  float sq = q0 * q0 + q1 * q1, sk = k0 * k0 + k1 * k1;
#pragma unroll
  for (int mm = 1; mm < 64; mm <<= 1) {
    sq += __shfl_xor(sq, mm);
    sk += __shfl_xor(sk, mm);
  }
  float rq = rsqrtf(sq * (1.f / 128.f) + 1e-5f);
  float rk = rsqrtf(sk * (1.f / 128.f) + 1e-5f);
  const float* wq = sp ? nq : naq;
  const float* wk = sp ? nk : nak;
  q0 *= rq * wq[e]; q1 *= rq * wq[e + 1];
  k0 *= rk * wk[e]; k1 *= rk * wk[e + 1];
  if (sp) {
    float c0 = ctab[s * 128 + e], c1 = ctab[s * 128 + e + 1];
    float s0 = stab[s * 128 + e], s1 = stab[s * 128 + e + 1];
    float a0 = q0 * c0 - q1 * s0, a1 = q1 * c1 + q0 * s1;
    float b0 = k0 * c0 - k1 * s0, b1 = k1 * c1 + k0 * s1;
    q0 = a0; q1 = a1; k0 = b0; k1 = b1;
  }
  const float scale = 0.08838834764831845f;  // 1/sqrt(128), folded into Q
  q0 *= scale; q1 *= scale;
  size_t o = (size_t)h * 2304 * 128 + (size_t)s * 128 + e;
  *(ushort2*)&Qf[o] = make_ushort2(f2bf(q0), f2bf(q1));
  *(ushort2*)&Kf[o] = make_ushort2(f2bf(k0), f2bf(k1));
  *(ushort2*)&Vf[o] = vu;
}

// ---------------------------------------------------------------------------
// flash attention, XOR-swizzled LDS (T2), 2 barriers/tile, defer-max (T13)
// block = (head, 64-query tile), 4 waves x 16 queries; KVBLK=64
// LDS layouts: logical chunk (16B) at physical chunk (c ^ (row&7)) within row
//   K: [64 rows][16 chunks]   V: [128 rows][8 chunks]   P: per-warp [16][8]
// global_load_lds writes linearly -> inverse-swizzle the per-lane SOURCE col
// ---------------------------------------------------------------------------
__global__ __launch_bounds__(256, 4) void attn_fwd(
    const unsigned short* __restrict__ Qf, const unsigned short* __restrict__ Kf,
    const unsigned short* __restrict__ Vt, unsigned short* __restrict__ Om)
{
  __shared__ unsigned short lsK[64 * 128];
  __shared__ unsigned short lsV[128 * 64];
  __shared__ unsigned short lsP[4 * 16 * 64];
  int h = blockIdx.x / 36, qt = blockIdx.x % 36;
  int q0 = qt * 64;
  int tid = threadIdx.x, w = tid >> 6, lane = tid & 63;
  int l15 = lane & 15, lhi = lane >> 4;
  const size_t headO = (size_t)h * 2304 * 128;

  short8 qf[4];
  {
    const unsigned short* qrow = Qf + headO + (size_t)(q0 + w * 16 + l15) * 128;
#pragma unroll
    for (int kk = 0; kk < 4; ++kk)
      qf[kk] = *(const short8*)&qrow[kk * 32 + lhi * 8];
  }
  float m[4], lsum[4];
  f32x4 accO[8];
#pragma unroll
  for (int r = 0; r < 4; ++r) { m[r] = -1e30f; lsum[r] = 0.f; }
#pragma unroll
  for (int t = 0; t < 8; ++t) accO[t] = (f32x4){0.f, 0.f, 0.f, 0.f};

  // staging: linear LDS dest chunk c; source col = (c&mask) ^ (row&7)
  size_t kGo[4], vGo[4];
  int loff[4];
#pragma unroll
  for (int j = 0; j < 4; ++j) {
    int c = j * 256 + w * 64 + lane;
    int krow = c >> 4, kcol = (c & 15) ^ (krow & 7);
    int vrow = c >> 3, vcol = (c & 7) ^ (vrow & 7);
    kGo[j] = (size_t)krow * 128 + kcol * 8;
    vGo[j] = (size_t)vrow * 2304 + vcol * 8;
    loff[j] = (j * 256 + w * 64) * 16;
  }
  const unsigned short* kbase0 = Kf + headO;
  const unsigned short* vbase0 = Vt + headO;
  char* pb = (char*)lsP + w * 2048;   // per-warp P region [16 rows][128 B]

  for (int kb = 0; kb < 2304; kb += 64) {
#pragma unroll
    for (int j = 0; j < 4; ++j) {
      gload16(kbase0 + (size_t)kb * 128 + kGo[j], (char*)lsK + loff[j]);
      gload16(vbase0 + kb + vGo[j], (char*)lsV + loff[j]);
    }
    __syncthreads();

    // S = Q K^T : 16 query rows x 64 keys (scale pre-folded into Q)
    f32x4 accS[4];
#pragma unroll
    for (int ct = 0; ct < 4; ++ct) {
      accS[ct] = (f32x4){0.f, 0.f, 0.f, 0.f};
#pragma unroll
      for (int kk = 0; kk < 4; ++kk) {
        int row = ct * 16 + l15;
        short8 kfr = *(const short8*)((char*)lsK + row * 256 +
                        (((kk * 4 + lhi) ^ (row & 7)) << 4));
        accS[ct] = __builtin_amdgcn_mfma_f32_16x16x32_bf16(qf[kk], kfr, accS[ct], 0, 0, 0);
      }
    }

    // online softmax with defer-max (THR=8)
#pragma unroll
    for (int r = 0; r < 4; ++r) {
      float s0 = accS[0][r], s1 = accS[1][r], s2 = accS[2][r], s3 = accS[3][r];
      float tmax = fmaxf(fmaxf(s0, s1), fmaxf(s2, s3));
#pragma unroll
      for (int mm = 1; mm < 16; mm <<= 1) tmax = fmaxf(tmax, __shfl_xor(tmax, mm));
      if (!__all(tmax <= m[r] + 8.0f)) {
        float mnew = fmaxf(m[r], tmax);
        float corr = __expf(m[r] - mnew);
        lsum[r] *= corr;
#pragma unroll
        for (int t = 0; t < 8; ++t) accO[t][r] *= corr;
        m[r] = mnew;
      }
      float p0 = __expf(s0 - m[r]), p1 = __expf(s1 - m[r]);
      float p2 = __expf(s2 - m[r]), p3 = __expf(s3 - m[r]);
      float psum = p0 + p1 + p2 + p3;
#pragma unroll
      for (int mm = 1; mm < 16; mm <<= 1) psum += __shfl_xor(psum, mm);
      lsum[r] += psum;
      int rowl = lhi * 4 + r;
      int ib = (2 * l15) & 15;      // byte within 16B chunk
      int c0 = (l15 >> 3);          // chunk bit from col
      float pv[4] = {p0, p1, p2, p3};
#pragma unroll
      for (int k = 0; k < 4; ++k) {
        int off = rowl * 128 + (((c0 + 2 * k) ^ (rowl & 7)) << 4) + ib;
        *(unsigned short*)(pb + off) = f2bf(pv[k]);
      }
    }

    // O += P V   (P warp-private: wave-local lgkm ordering suffices)
#pragma unroll
    for (int kk = 0; kk < 2; ++kk) {
      short8 pf = *(const short8*)(pb + l15 * 128 +
                     (((kk * 4 + lhi) ^ (l15 & 7)) << 4));
#pragma unroll
      for (int et = 0; et < 8; ++et) {
        int row = et * 16 + l15;
        short8 vf = *(const short8*)((char*)lsV + row * 128 +
                       (((kk * 4 + lhi) ^ (row & 7)) << 4));
        accO[et] = __builtin_amdgcn_mfma_f32_16x16x32_bf16(pf, vf, accO[et], 0, 0, 0);
      }
    }
    __syncthreads();
  }

#pragma unroll
  for (int r = 0; r < 4; ++r) {
    float inv = 1.0f / lsum[r];
    int row = q0 + w * 16 + lhi * 4 + r;
    unsigned short* orow = Om + (size_t)row * 3072 + h * 128;
#pragma unroll
    for (int et = 0; et < 8; ++et)
      orow[et * 16 + l15] = f2bf(accO[et][r] * inv);
  }
}

// ---------------------------------------------------------------------------
extern "C" void kernel_launch(void* const* d_in, const int* in_sizes, int n_in,
                              void* d_out, int out_size, void* d_ws, size_t ws_size,
                              hipStream_t stream)
{
  const float* spatial      = (const float*)d_in[0];
  const float* prompt       = (const float*)d_in[1];
  const float* w_qkv        = (const float*)d_in[2];
  const float* w_add_qkv    = (const float*)d_in[3];
  const float* b_add_qkv    = (const float*)d_in[4];
  const float* norm_q_w     = (const float*)d_in[5];
  const float* norm_k_w     = (const float*)d_in[6];
  const float* norm_add_q_w = (const float*)d_in[7];
  const float* norm_add_k_w = (const float*)d_in[8];
  const float* w_out        = (const float*)d_in[9];
  const float* b_out        = (const float*)d_in[10];
  const float* w_add_out    = (const float*)d_in[11];
  const float* b_add_out    = (const float*)d_in[12];
  const float* rope_cos     = (const float*)d_in[13];
  const float* rope_sin     = (const float*)d_in[14];

  constexpr size_t O_WTQ  = 0;
  constexpr size_t O_WTAQ = 56623104;
  constexpr size_t O_SPAT = 84934656;
  constexpr size_t O_PROM = 97517568;
  constexpr size_t O_QKV  = 98304000;
  constexpr size_t O_AQKV = 136052736;
  constexpr size_t O_QF   = 140771328;
  constexpr size_t O_KF   = 154927104;
  constexpr size_t O_VF   = 169082880;
  constexpr size_t TOTAL  = 183238656;
  constexpr size_t O_WTO  = O_WTQ;
  constexpr size_t O_WTAO = O_WTQ + 18874368;
  constexpr size_t O_VT   = O_QKV;
  constexpr size_t O_ATTN = O_WTAQ;
  if (ws_size < TOTAL) return;

  char* ws = (char*)d_ws;
  unsigned short* wTq      = (unsigned short*)(ws + O_WTQ);
  unsigned short* wTaq     = (unsigned short*)(ws + O_WTAQ);
  unsigned short* spat_bf  = (unsigned short*)(ws + O_SPAT);
  unsigned short* prom_bf  = (unsigned short*)(ws + O_PROM);
  unsigned short* qkv_s    = (unsigned short*)(ws + O_QKV);
  unsigned short* aqkv     = (unsigned short*)(ws + O_AQKV);
  unsigned short* Qf       = (unsigned short*)(ws + O_QF);
  unsigned short* Kf       = (unsigned short*)(ws + O_KF);
  unsigned short* Vf       = (unsigned short*)(ws + O_VF);
  unsigned short* wTo      = (unsigned short*)(ws + O_WTO);
  unsigned short* wTao     = (unsigned short*)(ws + O_WTAO);
  unsigned short* Vt       = (unsigned short*)(ws + O_VT);
  unsigned short* attn_out = (unsigned short*)(ws + O_ATTN);

  f32_to_bf16_kern<<<2048, 256, 0, stream>>>(spatial, spat_bf, 2048 * 3072 / 4);
  f32_to_bf16_kern<<<384, 256, 0, stream>>>(prompt, prom_bf, 256 * 1536 / 4);
  transpose_f32_bf16<<<dim3(144, 48), 256, 0, stream>>>(w_qkv, wTq, 3072, 9216);
  transpose_f32_bf16<<<dim3(144, 24), 256, 0, stream>>>(w_add_qkv, wTaq, 1536, 9216);
  gemm_bt<0, 1><<<dim3(72, 16), 256, 0, stream>>>(spat_bf, wTq, nullptr, qkv_s, 2048, 9216, 3072);
  gemm_bt<1, 1><<<dim3(72, 2), 256, 0, stream>>>(prom_bf, wTaq, b_add_qkv, aqkv, 256, 9216, 1536);
  fuse_rms_rope<<<13824, 256, 0, stream>>>(qkv_s, aqkv, norm_q_w, norm_k_w,
                                           norm_add_q_w, norm_add_k_w,
                                           rope_cos, rope_sin, Qf, Kf, Vf);
  transpose_bf16_64<<<dim3(2, 36, 24), 256, 0, stream>>>(Vf, Vt, 2304, 128);
  attn_fwd<<<24 * 36, 256, 0, stream>>>(Qf, Kf, Vt, attn_out);
  transpose_f32_bf16<<<dim3(48, 48), 256, 0, stream>>>(w_out, wTo, 3072, 3072);
  transpose_f32_bf16<<<dim3(48, 48), 256, 0, stream>>>(w_add_out, wTao, 3072, 3072);
  gemm_bt<1, 0><<<dim3(24, 16), 256, 0, stream>>>(attn_out, wTo, b_out,
                                                  (float*)d_out, 2048, 3072, 3072);
  gemm_bt<1, 0><<<dim3(24, 2), 256, 0, stream>>>(attn_out + (size_t)2048 * 3072, wTao, b_add_out,
                                                 (float*)d_out + 6291456, 256, 3072, 3072);
}

// Round 3
// 548.724 us; speedup vs baseline: 1.3520x; 1.0865x over previous
//
#include <hip/hip_runtime.h>
#include <cstdint>
#include <cstddef>

typedef __attribute__((ext_vector_type(8))) short short8;
typedef __attribute__((ext_vector_type(4))) float f32x4;

#define DEVI static __device__ __forceinline__

DEVI float bf2f(unsigned short b) {
  union { unsigned int u; float f; } v; v.u = ((unsigned int)b) << 16; return v.f;
}
DEVI unsigned short f2bf(float f) {
  union { float f; unsigned int u; } v; v.f = f;
  unsigned int r = v.u + 0x7fffu + ((v.u >> 16) & 1u);   // RTNE
  return (unsigned short)(r >> 16);
}

DEVI void gload16(const void* g, void* l) {
  __builtin_amdgcn_global_load_lds(
      (const __attribute__((address_space(1))) void*)g,
      (__attribute__((address_space(3))) void*)l, 16, 0, 0);
}

// ---------------------------------------------------------------------------
// elementwise f32 -> bf16 (vectorized float4 -> ushort4)
// ---------------------------------------------------------------------------
__global__ __launch_bounds__(256) void f32_to_bf16_kern(
    const float* __restrict__ in, unsigned short* __restrict__ out, int n4)
{
  int i = blockIdx.x * blockDim.x + threadIdx.x;
  int stride = gridDim.x * blockDim.x;
  for (; i < n4; i += stride) {
    float4 f = ((const float4*)in)[i];
    ushort4 u;
    u.x = f2bf(f.x); u.y = f2bf(f.y); u.z = f2bf(f.z); u.w = f2bf(f.w);
    ((ushort4*)out)[i] = u;
  }
}

// ---------------------------------------------------------------------------
// transpose + convert: in f32 [Kd][Nd]  ->  out bf16 [Nd][Kd]   (64x64 tiles)
// ---------------------------------------------------------------------------
__global__ __launch_bounds__(256) void transpose_f32_bf16(
    const float* __restrict__ in, unsigned short* __restrict__ out, int Kd, int Nd)
{
  __shared__ unsigned short tile[64][72];
  int n0 = blockIdx.x * 64, k0 = blockIdx.y * 64;
  int t = threadIdx.x;
  int r = t >> 2, cg = (t & 3) * 16;
  const float* src = in + (size_t)(k0 + r) * Nd + n0 + cg;
#pragma unroll
  for (int q = 0; q < 16; q += 4) {
    float4 f = *(const float4*)(src + q);
    ushort4 u;
    u.x = f2bf(f.x); u.y = f2bf(f.y); u.z = f2bf(f.z); u.w = f2bf(f.w);
    *(ushort4*)&tile[r][cg + q] = u;
  }
  __syncthreads();
  unsigned int p[8];
#pragma unroll
  for (int q = 0; q < 8; ++q)
    p[q] = (unsigned int)tile[cg + 2*q][r] | ((unsigned int)tile[cg + 2*q + 1][r] << 16);
  unsigned short* dst = out + (size_t)(n0 + r) * Kd + k0 + cg;
  *(uint4*)dst       = make_uint4(p[0], p[1], p[2], p[3]);
  *(uint4*)(dst + 8) = make_uint4(p[4], p[5], p[6], p[7]);
}

// ---------------------------------------------------------------------------
// bf16 transpose per head: in [rows][cols] -> out [cols][rows], 64x64 tiles
// ---------------------------------------------------------------------------
__global__ __launch_bounds__(256) void transpose_bf16_64(
    const unsigned short* __restrict__ in, unsigned short* __restrict__ out,
    int rows, int cols)
{
  __shared__ unsigned short tile[64][72];
  size_t hoff = (size_t)blockIdx.z * rows * cols;
  int e0 = blockIdx.x * 64, s0 = blockIdx.y * 64;
  int t = threadIdx.x;
  int r = t >> 2, cg = (t & 3) * 16;
  const unsigned short* src = in + hoff + (size_t)(s0 + r) * cols + e0 + cg;
  *(uint4*)&tile[r][cg]     = *(const uint4*)src;
  *(uint4*)&tile[r][cg + 8] = *(const uint4*)(src + 8);
  __syncthreads();
  unsigned int p[8];
#pragma unroll
  for (int q = 0; q < 8; ++q)
    p[q] = (unsigned int)tile[cg + 2*q][r] | ((unsigned int)tile[cg + 2*q + 1][r] << 16);
  unsigned short* dst = out + hoff + (size_t)(e0 + r) * rows + s0 + cg;
  *(uint4*)dst       = make_uint4(p[0], p[1], p[2], p[3]);
  *(uint4*)(dst + 8) = make_uint4(p[4], p[5], p[6], p[7]);
}

// ---------------------------------------------------------------------------
// GEMM: C[M][Nn] = A[M][K] * Bt[Nn][K]^T  (+bias), bf16 in, f32 acc
// 128x128 tile, BK=64, XOR-swizzled LDS (T2), XCD-swizzled 1D grid (T1)
// staging: linear LDS dest + inverse-swizzled per-lane global source (rule 21)
// ---------------------------------------------------------------------------
template<int HAS_BIAS, int OUT_BF16>
__global__ __launch_bounds__(256, 4) void gemm_bt(
    const unsigned short* __restrict__ A, const unsigned short* __restrict__ Bt,
    const float* __restrict__ bias, void* __restrict__ Cout,
    int M, int Nn, int K, int nby)
{
  __shared__ unsigned short lsA[128 * 64];
  __shared__ unsigned short lsB[128 * 64];
  const int tid = threadIdx.x;
  const int w = tid >> 6, lane = tid & 63;
  const int wr = w >> 1, wc = w & 1;
  const int l15 = lane & 15, lhi = lane >> 4;
  // XCD-aware bijective remap (gridDim.x % 8 == 0 for all our launches)
  const int nwg = gridDim.x, wg = blockIdx.x;
  const int swz = (wg & 7) * (nwg >> 3) + (wg >> 3);
  const int bx = swz / nby, by = swz - bx * nby;

  f32x4 acc[4][4];
#pragma unroll
  for (int i = 0; i < 4; ++i)
#pragma unroll
    for (int j = 0; j < 4; ++j) acc[i][j] = (f32x4){0.f, 0.f, 0.f, 0.f};

  // staging geometry: 16B chunk c = j*256+tid of a [128 rows][8 slots] tile
  // physical slot (c&7); logical slot = (c&7)^(row&7)  -> source column
  int srcoff[4];
#pragma unroll
  for (int j = 0; j < 4; ++j) {
    int c = j * 256 + tid;
    int row = c >> 3;
    int sl = (c & 7) ^ (row & 7);
    srcoff[j] = row * K + sl * 8;
  }
  const int wb = w * 1024;                       // wave-uniform LDS byte base
  const unsigned short* Abase = A + (size_t)(by * 128) * K;
  const unsigned short* Bbase = Bt + (size_t)(bx * 128) * K;

  for (int k0 = 0; k0 < K; k0 += 64) {
#pragma unroll
    for (int j = 0; j < 4; ++j) {
      gload16(Abase + srcoff[j] + k0, (char*)lsA + j * 4096 + wb);
      gload16(Bbase + srcoff[j] + k0, (char*)lsB + j * 4096 + wb);
    }
    __syncthreads();
#pragma unroll
    for (int kk = 0; kk < 2; ++kk) {
      const int sl = ((kk << 2) + lhi) ^ (l15 & 7);
      short8 af[4], bf[4];
#pragma unroll
      for (int t = 0; t < 4; ++t) {
        af[t] = *(const short8*)((char*)lsA + (wr * 64 + t * 16 + l15) * 128 + (sl << 4));
        bf[t] = *(const short8*)((char*)lsB + (wc * 64 + t * 16 + l15) * 128 + (sl << 4));
      }
#pragma unroll
      for (int mt = 0; mt < 4; ++mt)
#pragma unroll
        for (int nt = 0; nt < 4; ++nt)
          acc[mt][nt] = __builtin_amdgcn_mfma_f32_16x16x32_bf16(af[mt], bf[nt], acc[mt][nt], 0, 0, 0);
    }
    __syncthreads();
  }

  const int nbase = bx * 128 + wc * 64;
  const int mbase = by * 128 + wr * 64;
  float bv[4];
  if (HAS_BIAS) {
#pragma unroll
    for (int nt = 0; nt < 4; ++nt) bv[nt] = bias[nbase + nt * 16 + l15];
  }
#pragma unroll
  for (int mt = 0; mt < 4; ++mt)
#pragma unroll
    for (int nt = 0; nt < 4; ++nt) {
#pragma unroll
      for (int r2 = 0; r2 < 4; ++r2) {
        int m = mbase + mt * 16 + lhi * 4 + r2;
        int n = nbase + nt * 16 + l15;
        float v = acc[mt][nt][r2];
        if (HAS_BIAS) v += bv[nt];
        if (OUT_BF16) ((unsigned short*)Cout)[(size_t)m * Nn + n] = f2bf(v);
        else          ((float*)Cout)[(size_t)m * Nn + n] = v;
      }
    }
}

// ---------------------------------------------------------------------------
// fused RMSNorm + RoPE + head split/concat (+ fold softmax scale into Q)
// ---------------------------------------------------------------------------
__global__ __launch_bounds__(256) void fuse_rms_rope(
    const unsigned short* __restrict__ qkv,
    const unsigned short* __restrict__ aqkv,
    const float* __restrict__ nq, const float* __restrict__ nk,
    const float* __restrict__ naq, const float* __restrict__ nak,
    const float* __restrict__ ctab, const float* __restrict__ stab,
    unsigned short* __restrict__ Qf, unsigned short* __restrict__ Kf,
    unsigned short* __restrict__ Vf)
{
  int wid = blockIdx.x * 4 + (threadIdx.x >> 6);
  int lane = threadIdx.x & 63;
  int h = wid / 2304, s = wid % 2304;
  bool sp = (s < 2048);
  const unsigned short* src = sp ? (qkv + (size_t)s * 9216)
                                 : (aqkv + (size_t)(s - 2048) * 9216);
  int e = lane * 2;
  ushort2 qu = *(const ushort2*)&src[h * 128 + e];
  ushort2 ku = *(const ushort2*)&src[3072 + h * 128 + e];
  ushort2 vu = *(const ushort2*)&src[6144 + h * 128 + e];
  float q0 = bf2f(qu.x), q1 = bf2f(qu.y);
  float k0 = bf2f(ku.x), k1 = bf2f(ku.y);
  float sq = q0 * q0 + q1 * q1, sk = k0 * k0 + k1 * k1;
#pragma unroll
  for (int mm = 1; mm < 64; mm <<= 1) {
    sq += __shfl_xor(sq, mm);
    sk += __shfl_xor(sk, mm);
  }
  float rq = rsqrtf(sq * (1.f / 128.f) + 1e-5f);
  float rk = rsqrtf(sk * (1.f / 128.f) + 1e-5f);
  const float* wq = sp ? nq : naq;
  const float* wk = sp ? nk : nak;
  q0 *= rq * wq[e]; q1 *= rq * wq[e + 1];
  k0 *= rk * wk[e]; k1 *= rk * wk[e + 1];
  if (sp) {
    float c0 = ctab[s * 128 + e], c1 = ctab[s * 128 + e + 1];
    float s0 = stab[s * 128 + e], s1 = stab[s * 128 + e + 1];
    float a0 = q0 * c0 - q1 * s0, a1 = q1 * c1 + q0 * s1;
    float b0 = k0 * c0 - k1 * s0, b1 = k1 * c1 + k0 * s1;
    q0 = a0; q1 = a1; k0 = b0; k1 = b1;
  }
  const float scale = 0.08838834764831845f;  // 1/sqrt(128), folded into Q
  q0 *= scale; q1 *= scale;
  size_t o = (size_t)h * 2304 * 128 + (size_t)s * 128 + e;
  *(ushort2*)&Qf[o] = make_ushort2(f2bf(q0), f2bf(q1));
  *(ushort2*)&Kf[o] = make_ushort2(f2bf(k0), f2bf(k1));
  *(ushort2*)&Vf[o] = vu;
}

// ---------------------------------------------------------------------------
// flash attention, XOR-swizzled LDS (T2) + XCD chunking (T1) + setprio (T5)
// ---------------------------------------------------------------------------
__global__ __launch_bounds__(256, 4) void attn_fwd(
    const unsigned short* __restrict__ Qf, const unsigned short* __restrict__ Kf,
    const unsigned short* __restrict__ Vt, unsigned short* __restrict__ Om)
{
  __shared__ unsigned short lsK[64 * 128];
  __shared__ unsigned short lsV[128 * 64];
  __shared__ unsigned short lsP[4 * 16 * 64];
  // XCD chunking: 864 blocks -> 8 chunks of 108 (3 heads each)
  int wg = blockIdx.x;
  int swz = (wg & 7) * 108 + (wg >> 3);
  int h = swz / 36, qt = swz - h * 36;
  int q0 = qt * 64;
  int tid = threadIdx.x, w = tid >> 6, lane = tid & 63;
  int l15 = lane & 15, lhi = lane >> 4;
  const size_t headO = (size_t)h * 2304 * 128;

  short8 qf[4];
  {
    const unsigned short* qrow = Qf + headO + (size_t)(q0 + w * 16 + l15) * 128;
#pragma unroll
    for (int kk = 0; kk < 4; ++kk)
      qf[kk] = *(const short8*)&qrow[kk * 32 + lhi * 8];
  }
  float m[4], lsum[4];
  f32x4 accO[8];
#pragma unroll
  for (int r = 0; r < 4; ++r) { m[r] = -1e30f; lsum[r] = 0.f; }
#pragma unroll
  for (int t = 0; t < 8; ++t) accO[t] = (f32x4){0.f, 0.f, 0.f, 0.f};

  size_t kGo[4], vGo[4];
  int loff[4];
#pragma unroll
  for (int j = 0; j < 4; ++j) {
    int c = j * 256 + w * 64 + lane;
    int krow = c >> 4, kcol = (c & 15) ^ (krow & 7);
    int vrow = c >> 3, vcol = (c & 7) ^ (vrow & 7);
    kGo[j] = (size_t)krow * 128 + kcol * 8;
    vGo[j] = (size_t)vrow * 2304 + vcol * 8;
    loff[j] = (j * 256 + w * 64) * 16;
  }
  const unsigned short* kbase0 = Kf + headO;
  const unsigned short* vbase0 = Vt + headO;
  char* pb = (char*)lsP + w * 2048;

  for (int kb = 0; kb < 2304; kb += 64) {
#pragma unroll
    for (int j = 0; j < 4; ++j) {
      gload16(kbase0 + (size_t)kb * 128 + kGo[j], (char*)lsK + loff[j]);
      gload16(vbase0 + kb + vGo[j], (char*)lsV + loff[j]);
    }
    __syncthreads();

    f32x4 accS[4];
    __builtin_amdgcn_s_setprio(1);
#pragma unroll
    for (int ct = 0; ct < 4; ++ct) {
      accS[ct] = (f32x4){0.f, 0.f, 0.f, 0.f};
#pragma unroll
      for (int kk = 0; kk < 4; ++kk) {
        int row = ct * 16 + l15;
        short8 kfr = *(const short8*)((char*)lsK + row * 256 +
                        (((kk * 4 + lhi) ^ (row & 7)) << 4));
        accS[ct] = __builtin_amdgcn_mfma_f32_16x16x32_bf16(qf[kk], kfr, accS[ct], 0, 0, 0);
      }
    }
    __builtin_amdgcn_s_setprio(0);

#pragma unroll
    for (int r = 0; r < 4; ++r) {
      float s0 = accS[0][r], s1 = accS[1][r], s2 = accS[2][r], s3 = accS[3][r];
      float tmax = fmaxf(fmaxf(s0, s1), fmaxf(s2, s3));
#pragma unroll
      for (int mm = 1; mm < 16; mm <<= 1) tmax = fmaxf(tmax, __shfl_xor(tmax, mm));
      if (!__all(tmax <= m[r] + 8.0f)) {
        float mnew = fmaxf(m[r], tmax);
        float corr = __expf(m[r] - mnew);
        lsum[r] *= corr;
#pragma unroll
        for (int t = 0; t < 8; ++t) accO[t][r] *= corr;
        m[r] = mnew;
      }
      float p0 = __expf(s0 - m[r]), p1 = __expf(s1 - m[r]);
      float p2 = __expf(s2 - m[r]), p3 = __expf(s3 - m[r]);
      float psum = p0 + p1 + p2 + p3;
#pragma unroll
      for (int mm = 1; mm < 16; mm <<= 1) psum += __shfl_xor(psum, mm);
      lsum[r] += psum;
      int rowl = lhi * 4 + r;
      int ib = (2 * l15) & 15;
      int c0 = (l15 >> 3);
      float pv[4] = {p0, p1, p2, p3};
#pragma unroll
      for (int k = 0; k < 4; ++k) {
        int off = rowl * 128 + (((c0 + 2 * k) ^ (rowl & 7)) << 4) + ib;
        *(unsigned short*)(pb + off) = f2bf(pv[k]);
      }
    }

    __builtin_amdgcn_s_setprio(1);
#pragma unroll
    for (int kk = 0; kk < 2; ++kk) {
      short8 pf = *(const short8*)(pb + l15 * 128 +
                     (((kk * 4 + lhi) ^ (l15 & 7)) << 4));
#pragma unroll
      for (int et = 0; et < 8; ++et) {
        int row = et * 16 + l15;
        short8 vf = *(const short8*)((char*)lsV + row * 128 +
                       (((kk * 4 + lhi) ^ (row & 7)) << 4));
        accO[et] = __builtin_amdgcn_mfma_f32_16x16x32_bf16(pf, vf, accO[et], 0, 0, 0);
      }
    }
    __builtin_amdgcn_s_setprio(0);
    __syncthreads();
  }

#pragma unroll
  for (int r = 0; r < 4; ++r) {
    float inv = 1.0f / lsum[r];
    int row = q0 + w * 16 + lhi * 4 + r;
    unsigned short* orow = Om + (size_t)row * 3072 + h * 128;
#pragma unroll
    for (int et = 0; et < 8; ++et)
      orow[et * 16 + l15] = f2bf(accO[et][r] * inv);
  }
}

// ---------------------------------------------------------------------------
extern "C" void kernel_launch(void* const* d_in, const int* in_sizes, int n_in,
                              void* d_out, int out_size, void* d_ws, size_t ws_size,
                              hipStream_t stream)
{
  const float* spatial      = (const float*)d_in[0];
  const float* prompt       = (const float*)d_in[1];
  const float* w_qkv        = (const float*)d_in[2];
  const float* w_add_qkv    = (const float*)d_in[3];
  const float* b_add_qkv    = (const float*)d_in[4];
  const float* norm_q_w     = (const float*)d_in[5];
  const float* norm_k_w     = (const float*)d_in[6];
  const float* norm_add_q_w = (const float*)d_in[7];
  const float* norm_add_k_w = (const float*)d_in[8];
  const float* w_out        = (const float*)d_in[9];
  const float* b_out        = (const float*)d_in[10];
  const float* w_add_out    = (const float*)d_in[11];
  const float* b_add_out    = (const float*)d_in[12];
  const float* rope_cos     = (const float*)d_in[13];
  const float* rope_sin     = (const float*)d_in[14];

  constexpr size_t O_WTQ  = 0;
  constexpr size_t O_WTAQ = 56623104;
  constexpr size_t O_SPAT = 84934656;
  constexpr size_t O_PROM = 97517568;
  constexpr size_t O_QKV  = 98304000;
  constexpr size_t O_AQKV = 136052736;
  constexpr size_t O_QF   = 140771328;
  constexpr size_t O_KF   = 154927104;
  constexpr size_t O_VF   = 169082880;
  constexpr size_t TOTAL  = 183238656;
  constexpr size_t O_WTO  = O_WTQ;
  constexpr size_t O_WTAO = O_WTQ + 18874368;
  constexpr size_t O_VT   = O_QKV;
  constexpr size_t O_ATTN = O_WTAQ;
  if (ws_size < TOTAL) return;

  char* ws = (char*)d_ws;
  unsigned short* wTq      = (unsigned short*)(ws + O_WTQ);
  unsigned short* wTaq     = (unsigned short*)(ws + O_WTAQ);
  unsigned short* spat_bf  = (unsigned short*)(ws + O_SPAT);
  unsigned short* prom_bf  = (unsigned short*)(ws + O_PROM);
  unsigned short* qkv_s    = (unsigned short*)(ws + O_QKV);
  unsigned short* aqkv     = (unsigned short*)(ws + O_AQKV);
  unsigned short* Qf       = (unsigned short*)(ws + O_QF);
  unsigned short* Kf       = (unsigned short*)(ws + O_KF);
  unsigned short* Vf       = (unsigned short*)(ws + O_VF);
  unsigned short* wTo      = (unsigned short*)(ws + O_WTO);
  unsigned short* wTao     = (unsigned short*)(ws + O_WTAO);
  unsigned short* Vt       = (unsigned short*)(ws + O_VT);
  unsigned short* attn_out = (unsigned short*)(ws + O_ATTN);

  f32_to_bf16_kern<<<2048, 256, 0, stream>>>(spatial, spat_bf, 2048 * 3072 / 4);
  f32_to_bf16_kern<<<384, 256, 0, stream>>>(prompt, prom_bf, 256 * 1536 / 4);
  transpose_f32_bf16<<<dim3(144, 48), 256, 0, stream>>>(w_qkv, wTq, 3072, 9216);
  transpose_f32_bf16<<<dim3(144, 24), 256, 0, stream>>>(w_add_qkv, wTaq, 1536, 9216);
  gemm_bt<0, 1><<<1152, 256, 0, stream>>>(spat_bf, wTq, nullptr, qkv_s, 2048, 9216, 3072, 16);
  gemm_bt<1, 1><<<144, 256, 0, stream>>>(prom_bf, wTaq, b_add_qkv, aqkv, 256, 9216, 1536, 2);
  fuse_rms_rope<<<13824, 256, 0, stream>>>(qkv_s, aqkv, norm_q_w, norm_k_w,
                                           norm_add_q_w, norm_add_k_w,
                                           rope_cos, rope_sin, Qf, Kf, Vf);
  transpose_bf16_64<<<dim3(2, 36, 24), 256, 0, stream>>>(Vf, Vt, 2304, 128);
  attn_fwd<<<864, 256, 0, stream>>>(Qf, Kf, Vt, attn_out);
  transpose_f32_bf16<<<dim3(48, 48), 256, 0, stream>>>(w_out, wTo, 3072, 3072);
  transpose_f32_bf16<<<dim3(48, 48), 256, 0, stream>>>(w_add_out, wTao, 3072, 3072);
  gemm_bt<1, 0><<<384, 256, 0, stream>>>(attn_out, wTo, b_out,
                                         (float*)d_out, 2048, 3072, 3072, 16);
  gemm_bt<1, 0><<<48, 256, 0, stream>>>(attn_out + (size_t)2048 * 3072, wTao, b_add_out,
                                        (float*)d_out + 6291456, 256, 3072, 3072, 2);
}

// Round 6
// 505.370 us; speedup vs baseline: 1.4679x; 1.0858x over previous
//
#include <hip/hip_runtime.h>
#include <cstdint>
#include <cstddef>

typedef __attribute__((ext_vector_type(8))) short short8;
typedef __attribute__((ext_vector_type(4))) float f32x4;

#define DEVI static __device__ __forceinline__

DEVI float bf2f(unsigned short b) {
  union { unsigned int u; float f; } v; v.u = ((unsigned int)b) << 16; return v.f;
}
DEVI unsigned short f2bf(float f) {
  union { float f; unsigned int u; } v; v.f = f;
  unsigned int r = v.u + 0x7fffu + ((v.u >> 16) & 1u);   // RTNE
  return (unsigned short)(r >> 16);
}

DEVI void gload16(const void* g, void* l) {
  __builtin_amdgcn_global_load_lds(
      (const __attribute__((address_space(1))) void*)g,
      (__attribute__((address_space(3))) void*)l, 16, 0, 0);
}

// explicit LDS-DMA drain before barrier (belt-and-suspenders; round-3 shape)
DEVI void drain_ldsdma() {
  asm volatile("s_waitcnt vmcnt(0)" ::: "memory");
  __builtin_amdgcn_sched_barrier(0);
}

// ---------------------------------------------------------------------------
// elementwise f32 -> bf16 (vectorized float4 -> ushort4)
// ---------------------------------------------------------------------------
__global__ __launch_bounds__(256) void f32_to_bf16_kern(
    const float* __restrict__ in, unsigned short* __restrict__ out, int n4)
{
  int i = blockIdx.x * blockDim.x + threadIdx.x;
  int stride = gridDim.x * blockDim.x;
  for (; i < n4; i += stride) {
    float4 f = ((const float4*)in)[i];
    ushort4 u;
    u.x = f2bf(f.x); u.y = f2bf(f.y); u.z = f2bf(f.z); u.w = f2bf(f.w);
    ((ushort4*)out)[i] = u;
  }
}

// ---------------------------------------------------------------------------
// transpose + convert: in f32 [Kd][Nd]  ->  out bf16 [Nd][Kd]   (64x64 tiles)
// ---------------------------------------------------------------------------
__global__ __launch_bounds__(256) void transpose_f32_bf16(
    const float* __restrict__ in, unsigned short* __restrict__ out, int Kd, int Nd)
{
  __shared__ unsigned short tile[64][72];
  int n0 = blockIdx.x * 64, k0 = blockIdx.y * 64;
  int t = threadIdx.x;
  int r = t >> 2, cg = (t & 3) * 16;
  const float* src = in + (size_t)(k0 + r) * Nd + n0 + cg;
#pragma unroll
  for (int q = 0; q < 16; q += 4) {
    float4 f = *(const float4*)(src + q);
    ushort4 u;
    u.x = f2bf(f.x); u.y = f2bf(f.y); u.z = f2bf(f.z); u.w = f2bf(f.w);
    *(ushort4*)&tile[r][cg + q] = u;
  }
  __syncthreads();
  unsigned int p[8];
#pragma unroll
  for (int q = 0; q < 8; ++q)
    p[q] = (unsigned int)tile[cg + 2*q][r] | ((unsigned int)tile[cg + 2*q + 1][r] << 16);
  unsigned short* dst = out + (size_t)(n0 + r) * Kd + k0 + cg;
  *(uint4*)dst       = make_uint4(p[0], p[1], p[2], p[3]);
  *(uint4*)(dst + 8) = make_uint4(p[4], p[5], p[6], p[7]);
}

// ---------------------------------------------------------------------------
// bf16 transpose per head: in [rows][cols] -> out [cols][rows], 64x64 tiles
// ---------------------------------------------------------------------------
__global__ __launch_bounds__(256) void transpose_bf16_64(
    const unsigned short* __restrict__ in, unsigned short* __restrict__ out,
    int rows, int cols)
{
  __shared__ unsigned short tile[64][72];
  size_t hoff = (size_t)blockIdx.z * rows * cols;
  int e0 = blockIdx.x * 64, s0 = blockIdx.y * 64;
  int t = threadIdx.x;
  int r = t >> 2, cg = (t & 3) * 16;
  const unsigned short* src = in + hoff + (size_t)(s0 + r) * cols + e0 + cg;
  *(uint4*)&tile[r][cg]     = *(const uint4*)src;
  *(uint4*)&tile[r][cg + 8] = *(const uint4*)(src + 8);
  __syncthreads();
  unsigned int p[8];
#pragma unroll
  for (int q = 0; q < 8; ++q)
    p[q] = (unsigned int)tile[cg + 2*q][r] | ((unsigned int)tile[cg + 2*q + 1][r] << 16);
  unsigned short* dst = out + hoff + (size_t)(e0 + r) * rows + s0 + cg;
  *(uint4*)dst       = make_uint4(p[0], p[1], p[2], p[3]);
  *(uint4*)(dst + 8) = make_uint4(p[4], p[5], p[6], p[7]);
}

// ---------------------------------------------------------------------------
// GEMM: C[M][Nn] = A[M][K] * Bt[Nn][K]^T  (+bias), bf16 in, f32 acc
// 128x128 tile, BK=64, XOR-swizzled LDS (T2), XCD-swizzled 1D grid (T1)
// ---------------------------------------------------------------------------
template<int HAS_BIAS, int OUT_BF16>
__global__ __launch_bounds__(256, 4) void gemm_bt(
    const unsigned short* __restrict__ A, const unsigned short* __restrict__ Bt,
    const float* __restrict__ bias, void* __restrict__ Cout,
    int M, int Nn, int K, int nby)
{
  __shared__ unsigned short lsA[128 * 64];
  __shared__ unsigned short lsB[128 * 64];
  const int tid = threadIdx.x;
  const int w = tid >> 6, lane = tid & 63;
  const int wr = w >> 1, wc = w & 1;
  const int l15 = lane & 15, lhi = lane >> 4;
  const int nwg = gridDim.x, wg = blockIdx.x;
  const int swz = (wg & 7) * (nwg >> 3) + (wg >> 3);
  const int bx = swz / nby, by = swz - bx * nby;

  f32x4 acc[4][4];
#pragma unroll
  for (int i = 0; i < 4; ++i)
#pragma unroll
    for (int j = 0; j < 4; ++j) acc[i][j] = (f32x4){0.f, 0.f, 0.f, 0.f};

  int srcoff[4];
#pragma unroll
  for (int j = 0; j < 4; ++j) {
    int c = j * 256 + tid;
    int row = c >> 3;
    int sl = (c & 7) ^ (row & 7);
    srcoff[j] = row * K + sl * 8;
  }
  const int wb = w * 1024;
  const unsigned short* Abase = A + (size_t)(by * 128) * K;
  const unsigned short* Bbase = Bt + (size_t)(bx * 128) * K;

  for (int k0 = 0; k0 < K; k0 += 64) {
#pragma unroll
    for (int j = 0; j < 4; ++j) {
      gload16(Abase + srcoff[j] + k0, (char*)lsA + j * 4096 + wb);
      gload16(Bbase + srcoff[j] + k0, (char*)lsB + j * 4096 + wb);
    }
    __syncthreads();
#pragma unroll
    for (int kk = 0; kk < 2; ++kk) {
      const int sl = ((kk << 2) + lhi) ^ (l15 & 7);
      short8 af[4], bf[4];
#pragma unroll
      for (int t = 0; t < 4; ++t) {
        af[t] = *(const short8*)((char*)lsA + (wr * 64 + t * 16 + l15) * 128 + (sl << 4));
        bf[t] = *(const short8*)((char*)lsB + (wc * 64 + t * 16 + l15) * 128 + (sl << 4));
      }
#pragma unroll
      for (int mt = 0; mt < 4; ++mt)
#pragma unroll
        for (int nt = 0; nt < 4; ++nt)
          acc[mt][nt] = __builtin_amdgcn_mfma_f32_16x16x32_bf16(af[mt], bf[nt], acc[mt][nt], 0, 0, 0);
    }
    __syncthreads();
  }

  const int nbase = bx * 128 + wc * 64;
  const int mbase = by * 128 + wr * 64;
  float bv[4];
  if (HAS_BIAS) {
#pragma unroll
    for (int nt = 0; nt < 4; ++nt) bv[nt] = bias[nbase + nt * 16 + l15];
  }
#pragma unroll
  for (int mt = 0; mt < 4; ++mt)
#pragma unroll
    for (int nt = 0; nt < 4; ++nt) {
#pragma unroll
      for (int r2 = 0; r2 < 4; ++r2) {
        int m = mbase + mt * 16 + lhi * 4 + r2;
        int n = nbase + nt * 16 + l15;
        float v = acc[mt][nt][r2];
        if (HAS_BIAS) v += bv[nt];
        if (OUT_BF16) ((unsigned short*)Cout)[(size_t)m * Nn + n] = f2bf(v);
        else          ((float*)Cout)[(size_t)m * Nn + n] = v;
      }
    }
}

// ---------------------------------------------------------------------------
// fused RMSNorm + RoPE + head split/concat (+ fold softmax scale into Q)
// ---------------------------------------------------------------------------
__global__ __launch_bounds__(256) void fuse_rms_rope(
    const unsigned short* __restrict__ qkv,
    const unsigned short* __restrict__ aqkv,
    const float* __restrict__ nq, const float* __restrict__ nk,
    const float* __restrict__ naq, const float* __restrict__ nak,
    const float* __restrict__ ctab, const float* __restrict__ stab,
    unsigned short* __restrict__ Qf, unsigned short* __restrict__ Kf,
    unsigned short* __restrict__ Vf)
{
  int wid = blockIdx.x * 4 + (threadIdx.x >> 6);
  int lane = threadIdx.x & 63;
  int h = wid / 2304, s = wid % 2304;
  bool sp = (s < 2048);
  const unsigned short* src = sp ? (qkv + (size_t)s * 9216)
                                 : (aqkv + (size_t)(s - 2048) * 9216);
  int e = lane * 2;
  ushort2 qu = *(const ushort2*)&src[h * 128 + e];
  ushort2 ku = *(const ushort2*)&src[3072 + h * 128 + e];
  ushort2 vu = *(const ushort2*)&src[6144 + h * 128 + e];
  float q0 = bf2f(qu.x), q1 = bf2f(qu.y);
  float k0 = bf2f(ku.x), k1 = bf2f(ku.y);
  float sq = q0 * q0 + q1 * q1, sk = k0 * k0 + k1 * k1;
#pragma unroll
  for (int mm = 1; mm < 64; mm <<= 1) {
    sq += __shfl_xor(sq, mm);
    sk += __shfl_xor(sk, mm);
  }
  float rq = rsqrtf(sq * (1.f / 128.f) + 1e-5f);
  float rk = rsqrtf(sk * (1.f / 128.f) + 1e-5f);
  const float* wq = sp ? nq : naq;
  const float* wk = sp ? nk : nak;
  q0 *= rq * wq[e]; q1 *= rq * wq[e + 1];
  k0 *= rk * wk[e]; k1 *= rk * wk[e + 1];
  if (sp) {
    float c0 = ctab[s * 128 + e], c1 = ctab[s * 128 + e + 1];
    float s0 = stab[s * 128 + e], s1 = stab[s * 128 + e + 1];
    float a0 = q0 * c0 - q1 * s0, a1 = q1 * c1 + q0 * s1;
    float b0 = k0 * c0 - k1 * s0, b1 = k1 * c1 + k0 * s1;
    q0 = a0; q1 = a1; k0 = b0; k1 = b1;
  }
  const float scale = 0.08838834764831845f;  // 1/sqrt(128), folded into Q
  q0 *= scale; q1 *= scale;
  size_t o = (size_t)h * 2304 * 128 + (size_t)s * 128 + e;
  *(ushort2*)&Qf[o] = make_ushort2(f2bf(q0), f2bf(q1));
  *(ushort2*)&Kf[o] = make_ushort2(f2bf(k0), f2bf(k1));
  *(ushort2*)&Vf[o] = vu;
}

// ---------------------------------------------------------------------------
// flash attention: ROUND-3 sync structure (single K/V buffer, stage ->
// drain -> barrier -> compute -> barrier) + softmax diet only:
//   (B) per-lane lsum partials, reduced once at end
//   (C) local-max gate on the (rare) rescale path
// P-store: round-3 scalar f2bf (NO cvt_pk), same XOR-swizzled layout.
// ---------------------------------------------------------------------------
__global__ __launch_bounds__(256, 4) void attn_fwd(
    const unsigned short* __restrict__ Qf, const unsigned short* __restrict__ Kf,
    const unsigned short* __restrict__ Vt, unsigned short* __restrict__ Om)
{
  __shared__ unsigned short lsK[64 * 128];
  __shared__ unsigned short lsV[128 * 64];
  __shared__ unsigned short lsP[4 * 16 * 64];
  int wg = blockIdx.x;
  int swz = (wg & 7) * 108 + (wg >> 3);
  int h = swz / 36, qt = swz - h * 36;
  int q0 = qt * 64;
  int tid = threadIdx.x, w = tid >> 6, lane = tid & 63;
  int l15 = lane & 15, lhi = lane >> 4;
  const size_t headO = (size_t)h * 2304 * 128;

  short8 qf[4];
  {
    const unsigned short* qrow = Qf + headO + (size_t)(q0 + w * 16 + l15) * 128;
#pragma unroll
    for (int kk = 0; kk < 4; ++kk)
      qf[kk] = *(const short8*)&qrow[kk * 32 + lhi * 8];
  }
  float m[4], lsum[4];
  f32x4 accO[8];
#pragma unroll
  for (int r = 0; r < 4; ++r) { m[r] = -1e30f; lsum[r] = 0.f; }
#pragma unroll
  for (int t = 0; t < 8; ++t) accO[t] = (f32x4){0.f, 0.f, 0.f, 0.f};

  size_t kGo[4], vGo[4];
  int loff[4];
#pragma unroll
  for (int j = 0; j < 4; ++j) {
    int c = j * 256 + w * 64 + lane;
    int krow = c >> 4, kcol = (c & 15) ^ (krow & 7);
    int vrow = c >> 3, vcol = (c & 7) ^ (vrow & 7);
    kGo[j] = (size_t)krow * 128 + kcol * 8;
    vGo[j] = (size_t)vrow * 2304 + vcol * 8;
    loff[j] = (j * 256 + w * 64) * 16;
  }
  const unsigned short* kbase0 = Kf + headO;
  const unsigned short* vbase0 = Vt + headO;
  char* pb = (char*)lsP + w * 2048;

  for (int kb = 0; kb < 2304; kb += 64) {
    const unsigned short* kb_ = kbase0 + (size_t)kb * 128;
    const unsigned short* vb_ = vbase0 + kb;
#pragma unroll
    for (int j = 0; j < 4; ++j) {
      gload16(kb_ + kGo[j], (char*)lsK + loff[j]);
      gload16(vb_ + vGo[j], (char*)lsV + loff[j]);
    }
    drain_ldsdma();
    __syncthreads();

    // S = Q K^T (scale pre-folded into Q)
    f32x4 accS[4];
    __builtin_amdgcn_s_setprio(1);
#pragma unroll
    for (int ct = 0; ct < 4; ++ct) {
      accS[ct] = (f32x4){0.f, 0.f, 0.f, 0.f};
#pragma unroll
      for (int kk = 0; kk < 4; ++kk) {
        int row = ct * 16 + l15;
        short8 kfr = *(const short8*)((char*)lsK + row * 256 +
                        (((kk * 4 + lhi) ^ (row & 7)) << 4));
        accS[ct] = __builtin_amdgcn_mfma_f32_16x16x32_bf16(qf[kk], kfr, accS[ct], 0, 0, 0);
      }
    }
    __builtin_amdgcn_s_setprio(0);

    // softmax diet: gate + per-lane lsum partials
#pragma unroll
    for (int r = 0; r < 4; ++r) {
      float s0 = accS[0][r], s1 = accS[1][r], s2 = accS[2][r], s3 = accS[3][r];
      float lm = fmaxf(fmaxf(s0, s1), fmaxf(s2, s3));
      if (!__all(lm <= m[r] + 8.0f)) {          // rare rescale path
        float tmax = lm;
#pragma unroll
        for (int mm = 1; mm < 16; mm <<= 1) tmax = fmaxf(tmax, __shfl_xor(tmax, mm));
        float mnew = fmaxf(m[r], tmax);
        float corr = __expf(m[r] - mnew);
        lsum[r] *= corr;
#pragma unroll
        for (int t = 0; t < 8; ++t) accO[t][r] *= corr;
        m[r] = mnew;
      }
      float p0 = __expf(s0 - m[r]), p1 = __expf(s1 - m[r]);
      float p2 = __expf(s2 - m[r]), p3 = __expf(s3 - m[r]);
      lsum[r] += (p0 + p1) + (p2 + p3);
      int rowl = lhi * 4 + r;
      int ib = (2 * l15) & 15;
      int c0 = (l15 >> 3);
      int sw = rowl & 7;
      char* prow = pb + rowl * 128;
      float pv[4] = {p0, p1, p2, p3};
#pragma unroll
      for (int k = 0; k < 4; ++k)
        *(unsigned short*)(prow + (((c0 + 2 * k) ^ sw) << 4) + ib) = f2bf(pv[k]);
    }

    // O += P V
    __builtin_amdgcn_s_setprio(1);
#pragma unroll
    for (int kk = 0; kk < 2; ++kk) {
      short8 pf = *(const short8*)(pb + l15 * 128 +
                     (((kk * 4 + lhi) ^ (l15 & 7)) << 4));
#pragma unroll
      for (int et = 0; et < 8; ++et) {
        int row = et * 16 + l15;
        short8 vf = *(const short8*)((char*)lsV + row * 128 +
                       (((kk * 4 + lhi) ^ (row & 7)) << 4));
        accO[et] = __builtin_amdgcn_mfma_f32_16x16x32_bf16(pf, vf, accO[et], 0, 0, 0);
      }
    }
    __builtin_amdgcn_s_setprio(0);
    __syncthreads();
  }

  // one-time cross-lane lsum reduce (16-lane row groups)
#pragma unroll
  for (int r = 0; r < 4; ++r) {
#pragma unroll
    for (int mm = 1; mm < 16; mm <<= 1) lsum[r] += __shfl_xor(lsum[r], mm);
  }

#pragma unroll
  for (int r = 0; r < 4; ++r) {
    float inv = 1.0f / lsum[r];
    int row = q0 + w * 16 + lhi * 4 + r;
    unsigned short* orow = Om + (size_t)row * 3072 + h * 128;
#pragma unroll
    for (int et = 0; et < 8; ++et)
      orow[et * 16 + l15] = f2bf(accO[et][r] * inv);
  }
}

// ---------------------------------------------------------------------------
extern "C" void kernel_launch(void* const* d_in, const int* in_sizes, int n_in,
                              void* d_out, int out_size, void* d_ws, size_t ws_size,
                              hipStream_t stream)
{
  const float* spatial      = (const float*)d_in[0];
  const float* prompt       = (const float*)d_in[1];
  const float* w_qkv        = (const float*)d_in[2];
  const float* w_add_qkv    = (const float*)d_in[3];
  const float* b_add_qkv    = (const float*)d_in[4];
  const float* norm_q_w     = (const float*)d_in[5];
  const float* norm_k_w     = (const float*)d_in[6];
  const float* norm_add_q_w = (const float*)d_in[7];
  const float* norm_add_k_w = (const float*)d_in[8];
  const float* w_out        = (const float*)d_in[9];
  const float* b_out        = (const float*)d_in[10];
  const float* w_add_out    = (const float*)d_in[11];
  const float* b_add_out    = (const float*)d_in[12];
  const float* rope_cos     = (const float*)d_in[13];
  const float* rope_sin     = (const float*)d_in[14];

  constexpr size_t O_WTQ  = 0;
  constexpr size_t O_WTAQ = 56623104;
  constexpr size_t O_SPAT = 84934656;
  constexpr size_t O_PROM = 97517568;
  constexpr size_t O_QKV  = 98304000;
  constexpr size_t O_AQKV = 136052736;
  constexpr size_t O_QF   = 140771328;
  constexpr size_t O_KF   = 154927104;
  constexpr size_t O_VF   = 169082880;
  constexpr size_t TOTAL  = 183238656;
  constexpr size_t O_WTO  = O_WTQ;
  constexpr size_t O_WTAO = O_WTQ + 18874368;
  constexpr size_t O_VT   = O_QKV;
  constexpr size_t O_ATTN = O_WTAQ;
  if (ws_size < TOTAL) return;

  char* ws = (char*)d_ws;
  unsigned short* wTq      = (unsigned short*)(ws + O_WTQ);
  unsigned short* wTaq     = (unsigned short*)(ws + O_WTAQ);
  unsigned short* spat_bf  = (unsigned short*)(ws + O_SPAT);
  unsigned short* prom_bf  = (unsigned short*)(ws + O_PROM);
  unsigned short* qkv_s    = (unsigned short*)(ws + O_QKV);
  unsigned short* aqkv     = (unsigned short*)(ws + O_AQKV);
  unsigned short* Qf       = (unsigned short*)(ws + O_QF);
  unsigned short* Kf       = (unsigned short*)(ws + O_KF);
  unsigned short* Vf       = (unsigned short*)(ws + O_VF);
  unsigned short* wTo      = (unsigned short*)(ws + O_WTO);
  unsigned short* wTao     = (unsigned short*)(ws + O_WTAO);
  unsigned short* Vt       = (unsigned short*)(ws + O_VT);
  unsigned short* attn_out = (unsigned short*)(ws + O_ATTN);

  f32_to_bf16_kern<<<2048, 256, 0, stream>>>(spatial, spat_bf, 2048 * 3072 / 4);
  f32_to_bf16_kern<<<384, 256, 0, stream>>>(prompt, prom_bf, 256 * 1536 / 4);
  transpose_f32_bf16<<<dim3(144, 48), 256, 0, stream>>>(w_qkv, wTq, 3072, 9216);
  transpose_f32_bf16<<<dim3(144, 24), 256, 0, stream>>>(w_add_qkv, wTaq, 1536, 9216);
  gemm_bt<0, 1><<<1152, 256, 0, stream>>>(spat_bf, wTq, nullptr, qkv_s, 2048, 9216, 3072, 16);
  gemm_bt<1, 1><<<144, 256, 0, stream>>>(prom_bf, wTaq, b_add_qkv, aqkv, 256, 9216, 1536, 2);
  fuse_rms_rope<<<13824, 256, 0, stream>>>(qkv_s, aqkv, norm_q_w, norm_k_w,
                                           norm_add_q_w, norm_add_k_w,
                                           rope_cos, rope_sin, Qf, Kf, Vf);
  transpose_bf16_64<<<dim3(2, 36, 24), 256, 0, stream>>>(Vf, Vt, 2304, 128);
  attn_fwd<<<864, 256, 0, stream>>>(Qf, Kf, Vt, attn_out);
  transpose_f32_bf16<<<dim3(48, 48), 256, 0, stream>>>(w_out, wTo, 3072, 3072);
  transpose_f32_bf16<<<dim3(48, 48), 256, 0, stream>>>(w_add_out, wTao, 3072, 3072);
  gemm_bt<1, 0><<<384, 256, 0, stream>>>(attn_out, wTo, b_out,
                                         (float*)d_out, 2048, 3072, 3072, 16);
  gemm_bt<1, 0><<<48, 256, 0, stream>>>(attn_out + (size_t)2048 * 3072, wTao, b_add_out,
                                        (float*)d_out + 6291456, 256, 3072, 3072, 2);
}

// Round 7
// 477.085 us; speedup vs baseline: 1.5550x; 1.0593x over previous
//
#include <hip/hip_runtime.h>
#include <cstdint>
#include <cstddef>

typedef __attribute__((ext_vector_type(8))) short short8;
typedef __attribute__((ext_vector_type(4))) float f32x4;
typedef __attribute__((ext_vector_type(16))) float f32x16;

#define DEVI static __device__ __forceinline__

DEVI float bf2f(unsigned short b) {
  union { unsigned int u; float f; } v; v.u = ((unsigned int)b) << 16; return v.f;
}
DEVI unsigned short f2bf(float f) {
  union { float f; unsigned int u; } v; v.f = f;
  unsigned int r = v.u + 0x7fffu + ((v.u >> 16) & 1u);   // RTNE
  return (unsigned short)(r >> 16);
}
// pack two positive floats to bf16x2, round-half-up (5 ops, unbiased to 2^-9)
DEVI unsigned int pk2(float a, float b) {
  union { float f; unsigned int u; } ua, ub; ua.f = a; ub.f = b;
  return ((ua.u + 0x8000u) >> 16) | ((ub.u + 0x8000u) & 0xffff0000u);
}

DEVI void gload16(const void* g, void* l) {
  __builtin_amdgcn_global_load_lds(
      (const __attribute__((address_space(1))) void*)g,
      (__attribute__((address_space(3))) void*)l, 16, 0, 0);
}

DEVI void drain_ldsdma() {
  asm volatile("s_waitcnt vmcnt(0)" ::: "memory");
  __builtin_amdgcn_sched_barrier(0);
}

// ---------------------------------------------------------------------------
// elementwise f32 -> bf16 (vectorized float4 -> ushort4)
// ---------------------------------------------------------------------------
__global__ __launch_bounds__(256) void f32_to_bf16_kern(
    const float* __restrict__ in, unsigned short* __restrict__ out, int n4)
{
  int i = blockIdx.x * blockDim.x + threadIdx.x;
  int stride = gridDim.x * blockDim.x;
  for (; i < n4; i += stride) {
    float4 f = ((const float4*)in)[i];
    ushort4 u;
    u.x = f2bf(f.x); u.y = f2bf(f.y); u.z = f2bf(f.z); u.w = f2bf(f.w);
    ((ushort4*)out)[i] = u;
  }
}

// ---------------------------------------------------------------------------
// transpose + convert: in f32 [Kd][Nd]  ->  out bf16 [Nd][Kd]   (64x64 tiles)
// ---------------------------------------------------------------------------
__global__ __launch_bounds__(256) void transpose_f32_bf16(
    const float* __restrict__ in, unsigned short* __restrict__ out, int Kd, int Nd)
{
  __shared__ unsigned short tile[64][72];
  int n0 = blockIdx.x * 64, k0 = blockIdx.y * 64;
  int t = threadIdx.x;
  int r = t >> 2, cg = (t & 3) * 16;
  const float* src = in + (size_t)(k0 + r) * Nd + n0 + cg;
#pragma unroll
  for (int q = 0; q < 16; q += 4) {
    float4 f = *(const float4*)(src + q);
    ushort4 u;
    u.x = f2bf(f.x); u.y = f2bf(f.y); u.z = f2bf(f.z); u.w = f2bf(f.w);
    *(ushort4*)&tile[r][cg + q] = u;
  }
  __syncthreads();
  unsigned int p[8];
#pragma unroll
  for (int q = 0; q < 8; ++q)
    p[q] = (unsigned int)tile[cg + 2*q][r] | ((unsigned int)tile[cg + 2*q + 1][r] << 16);
  unsigned short* dst = out + (size_t)(n0 + r) * Kd + k0 + cg;
  *(uint4*)dst       = make_uint4(p[0], p[1], p[2], p[3]);
  *(uint4*)(dst + 8) = make_uint4(p[4], p[5], p[6], p[7]);
}

// ---------------------------------------------------------------------------
// bf16 transpose per head: in [rows][cols] -> out [cols][rows], 64x64 tiles
// ---------------------------------------------------------------------------
__global__ __launch_bounds__(256) void transpose_bf16_64(
    const unsigned short* __restrict__ in, unsigned short* __restrict__ out,
    int rows, int cols)
{
  __shared__ unsigned short tile[64][72];
  size_t hoff = (size_t)blockIdx.z * rows * cols;
  int e0 = blockIdx.x * 64, s0 = blockIdx.y * 64;
  int t = threadIdx.x;
  int r = t >> 2, cg = (t & 3) * 16;
  const unsigned short* src = in + hoff + (size_t)(s0 + r) * cols + e0 + cg;
  *(uint4*)&tile[r][cg]     = *(const uint4*)src;
  *(uint4*)&tile[r][cg + 8] = *(const uint4*)(src + 8);
  __syncthreads();
  unsigned int p[8];
#pragma unroll
  for (int q = 0; q < 8; ++q)
    p[q] = (unsigned int)tile[cg + 2*q][r] | ((unsigned int)tile[cg + 2*q + 1][r] << 16);
  unsigned short* dst = out + hoff + (size_t)(e0 + r) * rows + s0 + cg;
  *(uint4*)dst       = make_uint4(p[0], p[1], p[2], p[3]);
  *(uint4*)(dst + 8) = make_uint4(p[4], p[5], p[6], p[7]);
}

// ---------------------------------------------------------------------------
// GEMM: C[M][Nn] = A[M][K] * Bt[Nn][K]^T  (+bias), bf16 in, f32 acc
// 128x128 tile, BK=64, XOR-swizzled LDS (T2), XCD-swizzled 1D grid (T1)
// ---------------------------------------------------------------------------
template<int HAS_BIAS, int OUT_BF16>
__global__ __launch_bounds__(256, 4) void gemm_bt(
    const unsigned short* __restrict__ A, const unsigned short* __restrict__ Bt,
    const float* __restrict__ bias, void* __restrict__ Cout,
    int M, int Nn, int K, int nby)
{
  __shared__ unsigned short lsA[128 * 64];
  __shared__ unsigned short lsB[128 * 64];
  const int tid = threadIdx.x;
  const int w = tid >> 6, lane = tid & 63;
  const int wr = w >> 1, wc = w & 1;
  const int l15 = lane & 15, lhi = lane >> 4;
  const int nwg = gridDim.x, wg = blockIdx.x;
  const int swz = (wg & 7) * (nwg >> 3) + (wg >> 3);
  const int bx = swz / nby, by = swz - bx * nby;

  f32x4 acc[4][4];
#pragma unroll
  for (int i = 0; i < 4; ++i)
#pragma unroll
    for (int j = 0; j < 4; ++j) acc[i][j] = (f32x4){0.f, 0.f, 0.f, 0.f};

  int srcoff[4];
#pragma unroll
  for (int j = 0; j < 4; ++j) {
    int c = j * 256 + tid;
    int row = c >> 3;
    int sl = (c & 7) ^ (row & 7);
    srcoff[j] = row * K + sl * 8;
  }
  const int wb = w * 1024;
  const unsigned short* Abase = A + (size_t)(by * 128) * K;
  const unsigned short* Bbase = Bt + (size_t)(bx * 128) * K;

  for (int k0 = 0; k0 < K; k0 += 64) {
#pragma unroll
    for (int j = 0; j < 4; ++j) {
      gload16(Abase + srcoff[j] + k0, (char*)lsA + j * 4096 + wb);
      gload16(Bbase + srcoff[j] + k0, (char*)lsB + j * 4096 + wb);
    }
    __syncthreads();
#pragma unroll
    for (int kk = 0; kk < 2; ++kk) {
      const int sl = ((kk << 2) + lhi) ^ (l15 & 7);
      short8 af[4], bf[4];
#pragma unroll
      for (int t = 0; t < 4; ++t) {
        af[t] = *(const short8*)((char*)lsA + (wr * 64 + t * 16 + l15) * 128 + (sl << 4));
        bf[t] = *(const short8*)((char*)lsB + (wc * 64 + t * 16 + l15) * 128 + (sl << 4));
      }
#pragma unroll
      for (int mt = 0; mt < 4; ++mt)
#pragma unroll
        for (int nt = 0; nt < 4; ++nt)
          acc[mt][nt] = __builtin_amdgcn_mfma_f32_16x16x32_bf16(af[mt], bf[nt], acc[mt][nt], 0, 0, 0);
    }
    __syncthreads();
  }

  const int nbase = bx * 128 + wc * 64;
  const int mbase = by * 128 + wr * 64;
  float bv[4];
  if (HAS_BIAS) {
#pragma unroll
    for (int nt = 0; nt < 4; ++nt) bv[nt] = bias[nbase + nt * 16 + l15];
  }
#pragma unroll
  for (int mt = 0; mt < 4; ++mt)
#pragma unroll
    for (int nt = 0; nt < 4; ++nt) {
#pragma unroll
      for (int r2 = 0; r2 < 4; ++r2) {
        int m = mbase + mt * 16 + lhi * 4 + r2;
        int n = nbase + nt * 16 + l15;
        float v = acc[mt][nt][r2];
        if (HAS_BIAS) v += bv[nt];
        if (OUT_BF16) ((unsigned short*)Cout)[(size_t)m * Nn + n] = f2bf(v);
        else          ((float*)Cout)[(size_t)m * Nn + n] = v;
      }
    }
}

// ---------------------------------------------------------------------------
// fused RMSNorm + RoPE + head split/concat (+ fold softmax scale into Q)
// ---------------------------------------------------------------------------
__global__ __launch_bounds__(256) void fuse_rms_rope(
    const unsigned short* __restrict__ qkv,
    const unsigned short* __restrict__ aqkv,
    const float* __restrict__ nq, const float* __restrict__ nk,
    const float* __restrict__ naq, const float* __restrict__ nak,
    const float* __restrict__ ctab, const float* __restrict__ stab,
    unsigned short* __restrict__ Qf, unsigned short* __restrict__ Kf,
    unsigned short* __restrict__ Vf)
{
  int wid = blockIdx.x * 4 + (threadIdx.x >> 6);
  int lane = threadIdx.x & 63;
  int h = wid / 2304, s = wid % 2304;
  bool sp = (s < 2048);
  const unsigned short* src = sp ? (qkv + (size_t)s * 9216)
                                 : (aqkv + (size_t)(s - 2048) * 9216);
  int e = lane * 2;
  ushort2 qu = *(const ushort2*)&src[h * 128 + e];
  ushort2 ku = *(const ushort2*)&src[3072 + h * 128 + e];
  ushort2 vu = *(const ushort2*)&src[6144 + h * 128 + e];
  float q0 = bf2f(qu.x), q1 = bf2f(qu.y);
  float k0 = bf2f(ku.x), k1 = bf2f(ku.y);
  float sq = q0 * q0 + q1 * q1, sk = k0 * k0 + k1 * k1;
#pragma unroll
  for (int mm = 1; mm < 64; mm <<= 1) {
    sq += __shfl_xor(sq, mm);
    sk += __shfl_xor(sk, mm);
  }
  float rq = rsqrtf(sq * (1.f / 128.f) + 1e-5f);
  float rk = rsqrtf(sk * (1.f / 128.f) + 1e-5f);
  const float* wq = sp ? nq : naq;
  const float* wk = sp ? nk : nak;
  q0 *= rq * wq[e]; q1 *= rq * wq[e + 1];
  k0 *= rk * wk[e]; k1 *= rk * wk[e + 1];
  if (sp) {
    float c0 = ctab[s * 128 + e], c1 = ctab[s * 128 + e + 1];
    float s0 = stab[s * 128 + e], s1 = stab[s * 128 + e + 1];
    float a0 = q0 * c0 - q1 * s0, a1 = q1 * c1 + q0 * s1;
    float b0 = k0 * c0 - k1 * s0, b1 = k1 * c1 + k0 * s1;
    q0 = a0; q1 = a1; k0 = b0; k1 = b1;
  }
  const float scale = 0.08838834764831845f;  // 1/sqrt(128), folded into Q
  q0 *= scale; q1 *= scale;
  size_t o = (size_t)h * 2304 * 128 + (size_t)s * 128 + e;
  *(ushort2*)&Qf[o] = make_ushort2(f2bf(q0), f2bf(q1));
  *(ushort2*)&Kf[o] = make_ushort2(f2bf(k0), f2bf(k1));
  *(ushort2*)&Vf[o] = vu;
}

// ---------------------------------------------------------------------------
// flash attention v2: swapped QK^T on 32x32x16 MFMA, in-register softmax.
// block = (head, 128-query tile), 4 warps x 32 queries, KVBLK=64.
// Per warp/tile:
//   QK:  S^T = mfma(A=K_frag, B=Q_frag): C col=lane&31 -> query (lane-local),
//        row=(reg&3)+8*(reg>>2)+4*(lane>>5) -> key.
//   softmax: lane-local max/exp/sum + one shfl_xor(32) (partner holds the
//        other 16 keys/subtile). defer-max gate (THR=8), per-lane lsum.
//   P->PV A-frag: pack quads to bf16x2, one shfl_xor(32) per word pair:
//        frag(ks) e0-3 = h0-lane regs 8(ks&1)+4h+e, e4-7 = h1-lane same.
//   PV:  accO[dt] = mfma(A=P_frag, B=V_frag) over 4 key-slices x 4 d-tiles.
// Sync skeleton identical to round-6 (stage -> drain -> barrier -> compute
// -> barrier, single buffer). No P in LDS.
// ---------------------------------------------------------------------------
__global__ __launch_bounds__(256, 2) void attn_fwd(
    const unsigned short* __restrict__ Qf, const unsigned short* __restrict__ Kf,
    const unsigned short* __restrict__ Vt, unsigned short* __restrict__ Om)
{
  __shared__ unsigned short lsK[64 * 128];
  __shared__ unsigned short lsV[128 * 64];
  int wg = blockIdx.x;
  int swz = (wg & 7) * 54 + (wg >> 3);     // 432 blocks = 8 * 54
  int h = swz / 18, qt = swz - h * 18;
  int q0 = qt * 128;
  int tid = threadIdx.x, w = tid >> 6, lane = tid & 63;
  int l31 = lane & 31, hh = lane >> 5;
  const size_t headO = (size_t)h * 2304 * 128;

  // Q fragments: lane holds Q[q0+w*32+l31][s*16 + hh*8 + 0..7] for s=0..7
  short8 qf[8];
  {
    const unsigned short* qrow = Qf + headO + (size_t)(q0 + w * 32 + l31) * 128 + hh * 8;
#pragma unroll
    for (int s = 0; s < 8; ++s)
      qf[s] = *(const short8*)(qrow + s * 16);
  }

  float m_run = -1e30f, lsum = 0.f;
  f32x16 accO[4];
#pragma unroll
  for (int dt = 0; dt < 4; ++dt)
#pragma unroll
    for (int i = 0; i < 16; ++i) accO[dt][i] = 0.f;

  // staging (identical to round 6)
  size_t kGo[4], vGo[4];
  int loff[4];
#pragma unroll
  for (int j = 0; j < 4; ++j) {
    int c = j * 256 + w * 64 + lane;
    int krow = c >> 4, kcol = (c & 15) ^ (krow & 7);
    int vrow = c >> 3, vcol = (c & 7) ^ (vrow & 7);
    kGo[j] = (size_t)krow * 128 + kcol * 8;
    vGo[j] = (size_t)vrow * 2304 + vcol * 8;
    loff[j] = (j * 256 + w * 64) * 16;
  }
  const unsigned short* kbase0 = Kf + headO;
  const unsigned short* vbase0 = Vt + headO;

  for (int kb = 0; kb < 2304; kb += 64) {
    const unsigned short* kb_ = kbase0 + (size_t)kb * 128;
    const unsigned short* vb_ = vbase0 + kb;
#pragma unroll
    for (int j = 0; j < 4; ++j) {
      gload16(kb_ + kGo[j], (char*)lsK + loff[j]);
      gload16(vb_ + vGo[j], (char*)lsV + loff[j]);
    }
    drain_ldsdma();
    __syncthreads();

    // ---- QK^T (swapped): accS[t] = K_subtile_t x Q  (scale folded in Q)
    f32x16 accS[2];
#pragma unroll
    for (int t = 0; t < 2; ++t)
#pragma unroll
      for (int i = 0; i < 16; ++i) accS[t][i] = 0.f;
    __builtin_amdgcn_s_setprio(1);
#pragma unroll
    for (int t = 0; t < 2; ++t) {
      const int row = l31 + t * 32;
      const int rsw = row & 7;
#pragma unroll
      for (int s = 0; s < 8; ++s) {
        short8 kfr = *(const short8*)((char*)lsK + row * 256 +
                        (((s * 2 + hh) ^ rsw) << 4));
        accS[t] = __builtin_amdgcn_mfma_f32_32x32x16_bf16(kfr, qf[s], accS[t], 0, 0, 0);
      }
    }
    __builtin_amdgcn_s_setprio(0);

    // ---- softmax (lane-local; query = l31; keys split with partner lane^32)
    float lm = accS[0][0];
#pragma unroll
    for (int t = 0; t < 2; ++t)
#pragma unroll
      for (int i = 0; i < 16; ++i) lm = fmaxf(lm, accS[t][i]);
    float lmx = fmaxf(lm, __shfl_xor(lm, 32));
    if (!__all(lmx <= m_run + 8.0f)) {          // rare rescale path
      float mnew = fmaxf(m_run, lmx);
      float corr = __expf(m_run - mnew);
      lsum *= corr;
      float corrq[16];
#pragma unroll
      for (int r = 0; r < 16; ++r)
        corrq[r] = __shfl(corr, ((r & 3) + 8 * (r >> 2) + 4 * hh) | (lane & 32));
#pragma unroll
      for (int dt = 0; dt < 4; ++dt)
#pragma unroll
        for (int r = 0; r < 16; ++r) accO[dt][r] *= corrq[r];
      m_run = mnew;
    }
#pragma unroll
    for (int t = 0; t < 2; ++t)
#pragma unroll
      for (int i = 0; i < 16; ++i) {
        float p = __expf(accS[t][i] - m_run);
        accS[t][i] = p;
        lsum += p;
      }

    // ---- P -> PV A-fragments + PV
    __builtin_amdgcn_s_setprio(1);
#pragma unroll
    for (int ks = 0; ks < 4; ++ks) {
      const int t = ks >> 1;
      const int qlo = 8 * (ks & 1);
      unsigned int wlo0 = pk2(accS[t][qlo + 0], accS[t][qlo + 1]);
      unsigned int wlo1 = pk2(accS[t][qlo + 2], accS[t][qlo + 3]);
      unsigned int whi0 = pk2(accS[t][qlo + 4], accS[t][qlo + 5]);
      unsigned int whi1 = pk2(accS[t][qlo + 6], accS[t][qlo + 7]);
      unsigned int r0 = __shfl_xor(hh ? wlo0 : whi0, 32);
      unsigned int r1 = __shfl_xor(hh ? wlo1 : whi1, 32);
      unsigned int fw0 = hh ? r0 : wlo0;
      unsigned int fw1 = hh ? r1 : wlo1;
      unsigned int fw2 = hh ? whi0 : r0;
      unsigned int fw3 = hh ? whi1 : r1;
      unsigned int fwa[4] = {fw0, fw1, fw2, fw3};
      short8 paf = *(short8*)fwa;
#pragma unroll
      for (int dt = 0; dt < 4; ++dt) {
        const int row = dt * 32 + l31;
        short8 vfr = *(const short8*)((char*)lsV + row * 128 +
                        (((ks * 2 + hh) ^ (row & 7)) << 4));
        accO[dt] = __builtin_amdgcn_mfma_f32_32x32x16_bf16(paf, vfr, accO[dt], 0, 0, 0);
      }
    }
    __builtin_amdgcn_s_setprio(0);
    __syncthreads();
  }

  // ---- epilogue: combine partner lsum, normalize, write O
  lsum += __shfl_xor(lsum, 32);
  float inv = 1.0f / lsum;
  float invq[16];
#pragma unroll
  for (int r = 0; r < 16; ++r)
    invq[r] = __shfl(inv, ((r & 3) + 8 * (r >> 2) + 4 * hh) | (lane & 32));
#pragma unroll
  for (int dt = 0; dt < 4; ++dt)
#pragma unroll
    for (int r = 0; r < 16; ++r) {
      int qrow = (r & 3) + 8 * (r >> 2) + 4 * hh;
      int row = q0 + w * 32 + qrow;
      Om[(size_t)row * 3072 + h * 128 + dt * 32 + l31] = f2bf(accO[dt][r] * invq[r]);
    }
}

// ---------------------------------------------------------------------------
extern "C" void kernel_launch(void* const* d_in, const int* in_sizes, int n_in,
                              void* d_out, int out_size, void* d_ws, size_t ws_size,
                              hipStream_t stream)
{
  const float* spatial      = (const float*)d_in[0];
  const float* prompt       = (const float*)d_in[1];
  const float* w_qkv        = (const float*)d_in[2];
  const float* w_add_qkv    = (const float*)d_in[3];
  const float* b_add_qkv    = (const float*)d_in[4];
  const float* norm_q_w     = (const float*)d_in[5];
  const float* norm_k_w     = (const float*)d_in[6];
  const float* norm_add_q_w = (const float*)d_in[7];
  const float* norm_add_k_w = (const float*)d_in[8];
  const float* w_out        = (const float*)d_in[9];
  const float* b_out        = (const float*)d_in[10];
  const float* w_add_out    = (const float*)d_in[11];
  const float* b_add_out    = (const float*)d_in[12];
  const float* rope_cos     = (const float*)d_in[13];
  const float* rope_sin     = (const float*)d_in[14];

  constexpr size_t O_WTQ  = 0;
  constexpr size_t O_WTAQ = 56623104;
  constexpr size_t O_SPAT = 84934656;
  constexpr size_t O_PROM = 97517568;
  constexpr size_t O_QKV  = 98304000;
  constexpr size_t O_AQKV = 136052736;
  constexpr size_t O_QF   = 140771328;
  constexpr size_t O_KF   = 154927104;
  constexpr size_t O_VF   = 169082880;
  constexpr size_t TOTAL  = 183238656;
  constexpr size_t O_WTO  = O_WTQ;
  constexpr size_t O_WTAO = O_WTQ + 18874368;
  constexpr size_t O_VT   = O_QKV;
  constexpr size_t O_ATTN = O_WTAQ;
  if (ws_size < TOTAL) return;

  char* ws = (char*)d_ws;
  unsigned short* wTq      = (unsigned short*)(ws + O_WTQ);
  unsigned short* wTaq     = (unsigned short*)(ws + O_WTAQ);
  unsigned short* spat_bf  = (unsigned short*)(ws + O_SPAT);
  unsigned short* prom_bf  = (unsigned short*)(ws + O_PROM);
  unsigned short* qkv_s    = (unsigned short*)(ws + O_QKV);
  unsigned short* aqkv     = (unsigned short*)(ws + O_AQKV);
  unsigned short* Qf       = (unsigned short*)(ws + O_QF);
  unsigned short* Kf       = (unsigned short*)(ws + O_KF);
  unsigned short* Vf       = (unsigned short*)(ws + O_VF);
  unsigned short* wTo      = (unsigned short*)(ws + O_WTO);
  unsigned short* wTao     = (unsigned short*)(ws + O_WTAO);
  unsigned short* Vt       = (unsigned short*)(ws + O_VT);
  unsigned short* attn_out = (unsigned short*)(ws + O_ATTN);

  f32_to_bf16_kern<<<2048, 256, 0, stream>>>(spatial, spat_bf, 2048 * 3072 / 4);
  f32_to_bf16_kern<<<384, 256, 0, stream>>>(prompt, prom_bf, 256 * 1536 / 4);
  transpose_f32_bf16<<<dim3(144, 48), 256, 0, stream>>>(w_qkv, wTq, 3072, 9216);
  transpose_f32_bf16<<<dim3(144, 24), 256, 0, stream>>>(w_add_qkv, wTaq, 1536, 9216);
  gemm_bt<0, 1><<<1152, 256, 0, stream>>>(spat_bf, wTq, nullptr, qkv_s, 2048, 9216, 3072, 16);
  gemm_bt<1, 1><<<144, 256, 0, stream>>>(prom_bf, wTaq, b_add_qkv, aqkv, 256, 9216, 1536, 2);
  fuse_rms_rope<<<13824, 256, 0, stream>>>(qkv_s, aqkv, norm_q_w, norm_k_w,
                                           norm_add_q_w, norm_add_k_w,
                                           rope_cos, rope_sin, Qf, Kf, Vf);
  transpose_bf16_64<<<dim3(2, 36, 24), 256, 0, stream>>>(Vf, Vt, 2304, 128);
  attn_fwd<<<432, 256, 0, stream>>>(Qf, Kf, Vt, attn_out);
  transpose_f32_bf16<<<dim3(48, 48), 256, 0, stream>>>(w_out, wTo, 3072, 3072);
  transpose_f32_bf16<<<dim3(48, 48), 256, 0, stream>>>(w_add_out, wTao, 3072, 3072);
  gemm_bt<1, 0><<<384, 256, 0, stream>>>(attn_out, wTo, b_out,
                                         (float*)d_out, 2048, 3072, 3072, 16);
  gemm_bt<1, 0><<<48, 256, 0, stream>>>(attn_out + (size_t)2048 * 3072, wTao, b_add_out,
                                        (float*)d_out + 6291456, 256, 3072, 3072, 2);
}